// Round 11
// baseline (389.325 us; speedup 1.0000x reference)
//
#include <hip/hip_runtime.h>
#include <hip/hip_bf16.h>

// Problem constants (fixed by the reference file)
#define DIN   128
#define HID2  64
#define NCLS  10
#define NGRAPH 128
#define SCAN_CHUNK 1024
#define NBLK 256          // blocks in bhist/partition (edge assignment must match)
#define NBKT_MAX 512      // max buckets (nodes/256)
#define CAP 6144          // LDS src-staging capacity per bucket (mean 4096, +32 sigma)
#define EPB 6400          // max edges per partition block = ceil(E/65536)*256 (E=1.6M)

typedef __attribute__((ext_vector_type(8))) short bf16x8;
typedef __attribute__((ext_vector_type(4))) float f32x4;

__device__ __forceinline__ void atomAddF(float* p, float v) {
    unsafeAtomicAdd(p, v);
}

// float -> bf16 (round-to-nearest-even), finite inputs.
__device__ __forceinline__ unsigned short f2bf(float f) {
    unsigned int u = __float_as_uint(f);
    u += 0x7fffu + ((u >> 16) & 1u);
    return (unsigned short)(u >> 16);
}

// ---------- combined prep + radix pass 1 ----------
// Blocks [0, NBLK): per-(bucket,block) histogram bh[bkt*NBLK + blk];
//   block 0 also zeroes the pooling accumulators.
// Blocks [NBLK, NBLK+65): w12b = bf16((lin1_w @ conv1_w)^T) (2 rows/block)
//   and c1preb = lin1_b @ conv1_w. w12b is stored [c][k] so the GEMM reads
//   B-fragments directly from L2 (no LDS tile, no bank conflicts).
// Block NBLK+65: w2b = bf16(conv2_w^T) for the fused gather+GEMM.
__global__ __launch_bounds__(256) void k_bhist(const int* __restrict__ dst,
                                               int* __restrict__ bh, int E, int nbkt,
                                               float* __restrict__ zbuf, int zn,
                                               const float* __restrict__ lw,
                                               const float* __restrict__ lb,
                                               const float* __restrict__ cw,
                                               const float* __restrict__ cw2,
                                               unsigned short* __restrict__ w12b,
                                               float* __restrict__ c1preb,
                                               unsigned short* __restrict__ w2b) {
    const int tid = threadIdx.x;
    if (blockIdx.x >= NBLK) {
        const int bi = blockIdx.x - NBLK;
        if (bi == 65) {
            // w2b[c*128+k] = bf16(cw2[k*64+c]); 32KB source, L2-hot
            for (int f = tid; f < 8192; f += 256) w2b[f] = f2bf(cw2[(f & 127) * 64 + (f >> 7)]);
        } else {
            const int i = bi * 2 + (tid >> 7);   // 0..129 (129 skipped)
            if (i <= 128) {
                const int j = tid & 127;
                const float* arow = (i < 128) ? (lw + i * 128) : lb;
                float acc = 0.f;
#pragma unroll 8
                for (int k = 0; k < 128; ++k) acc += arow[k] * cw[k * 128 + j];
                if (i < 128) w12b[j * 128 + i] = f2bf(acc);   // transposed bf16
                else         c1preb[j] = acc;
            }
        }
        return;
    }
    __shared__ int lh[NBKT_MAX];
    if (blockIdx.x == 0)
        for (int i = tid; i < zn; i += 256) zbuf[i] = 0.f;
    for (int i = tid; i < nbkt; i += 256) lh[i] = 0;
    __syncthreads();
    for (int e = blockIdx.x * 256 + tid; e < E; e += NBLK * 256)
        atomicAdd(&lh[__builtin_nontemporal_load(dst + e) >> 8], 1);
    __syncthreads();
    for (int i = tid; i < nbkt; i += 256) bh[i * NBLK + blockIdx.x] = lh[i];
}

// --- 3-phase parallel exclusive scan (generic length; used on bh in-place) ---
__global__ __launch_bounds__(256) void k_scan_part(const int* __restrict__ cnt,
                                                   int* __restrict__ part, int n) {
    int base = blockIdx.x * SCAN_CHUNK + threadIdx.x * 4;
    int s = 0;
#pragma unroll
    for (int j = 0; j < 4; ++j) { int i = base + j; if (i < n) s += cnt[i]; }
#pragma unroll
    for (int o = 32; o > 0; o >>= 1) s += __shfl_down(s, o);
    __shared__ int wsum[4];
    if ((threadIdx.x & 63) == 0) wsum[threadIdx.x >> 6] = s;
    __syncthreads();
    if (threadIdx.x == 0) part[blockIdx.x] = wsum[0] + wsum[1] + wsum[2] + wsum[3];
}
__global__ __launch_bounds__(256) void k_scan_mid(int* __restrict__ part,
                                                  int* __restrict__ total_out,
                                                  int B, int n) {
    __shared__ int sh[256];
    int t = threadIdx.x;
    int v = (t < B) ? part[t] : 0;
    sh[t] = v;
    __syncthreads();
    for (int off = 1; off < 256; off <<= 1) {
        int u = (t >= off) ? sh[t - off] : 0;
        __syncthreads();
        sh[t] += u;
        __syncthreads();
    }
    if (t < B) part[t] = sh[t] - v;
    if (t == 255) total_out[n] = sh[255];
}
// in-place-safe (out may alias cnt: all reads precede a barrier before writes)
__global__ __launch_bounds__(256) void k_scan_fin2(const int* cnt,
                                                   const int* __restrict__ part,
                                                   int* out, int n) {
    __shared__ int sh[256];
    int t = threadIdx.x;
    int base = blockIdx.x * SCAN_CHUNK + t * 4;
    int c[4]; int s = 0;
#pragma unroll
    for (int j = 0; j < 4; ++j) { int i = base + j; c[j] = (i < n) ? cnt[i] : 0; s += c[j]; }
    sh[t] = s;
    __syncthreads();
    for (int off = 1; off < 256; off <<= 1) {
        int u = (t >= off) ? sh[t - off] : 0;
        __syncthreads();
        sh[t] += u;
        __syncthreads();
    }
    int excl = part[blockIdx.x] + sh[t] - s;
#pragma unroll
    for (int j = 0; j < 4; ++j) {
        int i = base + j;
        if (i < n) out[i] = excl;
        excl += c[j];
    }
}

// Pass 2: in-LDS counting sort, then COALESCED write-out of packed
// (src<<8 | dst&255) edges. Edge->block assignment identical to k_bhist.
__global__ __launch_bounds__(256) void k_partition(const int* __restrict__ src,
                                                   const int* __restrict__ dst,
                                                   const int* __restrict__ bh,
                                                   int* __restrict__ pairs, int E, int nbkt) {
    __shared__ int lh[NBKT_MAX];
    __shared__ int lscan[NBKT_MAX + 2];
    __shared__ int gofs[NBKT_MAX];
    __shared__ int lcur[NBKT_MAX];
    __shared__ int scanw[256];
    __shared__ int lbuf[EPB];
    const int tid = threadIdx.x;
    const int b = blockIdx.x;

    for (int i = tid; i < NBKT_MAX; i += 256) lh[i] = 0;
    __syncthreads();
    for (int e = b * 256 + tid; e < E; e += NBLK * 256)
        atomicAdd(&lh[__builtin_nontemporal_load(dst + e) >> 8], 1);
    __syncthreads();
    const int a0 = lh[2 * tid], a1 = lh[2 * tid + 1];
    const int ps = a0 + a1;
    scanw[tid] = ps;
    __syncthreads();
    for (int off = 1; off < 256; off <<= 1) {
        int u = (tid >= off) ? scanw[tid - off] : 0;
        __syncthreads();
        scanw[tid] += u;
        __syncthreads();
    }
    const int ex = scanw[tid] - ps;
    lscan[2 * tid] = ex;
    lscan[2 * tid + 1] = ex + a0;
    if (tid == 255) lscan[512] = scanw[255];
    __syncthreads();
#pragma unroll
    for (int q = 0; q < 2; ++q) {
        const int k = 2 * tid + q;
        lcur[k] = lscan[k];
        if (k < nbkt) gofs[k] = bh[k * NBLK + b] - lscan[k];
    }
    __syncthreads();
    for (int e = b * 256 + tid; e < E; e += NBLK * 256) {
        const int d = __builtin_nontemporal_load(dst + e);
        const int s = __builtin_nontemporal_load(src + e);
        const int lpos = atomicAdd(&lcur[d >> 8], 1);
        lbuf[lpos] = (s << 8) | (d & 255);
    }
    __syncthreads();
    const int cnt = lscan[512];
    for (int i = tid; i < cnt; i += 256) {
        int lo = 0, hi = nbkt;
        while (hi - lo > 1) {
            const int mid = (lo + hi) >> 1;
            if (lscan[mid] <= i) lo = mid; else hi = mid;
        }
        pairs[gofs[lo] + i] = lbuf[i];
    }
}

// Pass 3: one block per bucket. In-LDS degree count + scan + scatter, then
// coalesced single-touch streams: row_start, dis, col. No global atomics.
__global__ __launch_bounds__(256) void k_csr_local(const int* __restrict__ pairs,
                                                   const int* __restrict__ bh,
                                                   int* __restrict__ row_start,
                                                   float* __restrict__ dis,
                                                   int* __restrict__ col,
                                                   int N) {
    __shared__ int cntL[256], scanL[256], curL[256];
    __shared__ int srcbuf[CAP];
    const int tid = threadIdx.x;
    const int lo = blockIdx.x << 8;
    const int bstart = bh[blockIdx.x * NBLK];
    const int bend = bh[(blockIdx.x + 1) * NBLK];   // last bucket: bh[nbkt*NBLK] == E
    const int nE = bend - bstart;

    cntL[tid] = 0;
    __syncthreads();
    for (int e = bstart + tid; e < bend; e += 256)
        atomicAdd(&cntL[pairs[e] & 255], 1);
    __syncthreads();
    const int deg = cntL[tid];
    scanL[tid] = deg;
    __syncthreads();
    for (int off = 1; off < 256; off <<= 1) {
        int u = (tid >= off) ? scanL[tid - off] : 0;
        __syncthreads();
        scanL[tid] += u;
        __syncthreads();
    }
    const int excl = scanL[tid] - deg;
    curL[tid] = excl;
    const int node = lo + tid;
    if (node < N) {
        row_start[node] = bstart + excl;
        dis[node] = rsqrtf((float)(deg + 1));   // +1 self-loop
    } else if (node == N) {
        row_start[N] = bend;                    // == E (only last bucket reaches here)
    }
    __syncthreads();
    if (nE <= CAP) {
        for (int e = bstart + tid; e < bend; e += 256) {
            int p = pairs[e];
            int pos = atomicAdd(&curL[p & 255], 1);
            srcbuf[pos] = ((unsigned int)p) >> 8;
        }
        __syncthreads();
        for (int i = tid; i < nE; i += 256)
            col[bstart + i] = srcbuf[i];
    } else {  // overflow fallback (statistically never for random graphs)
        for (int e = bstart + tid; e < bend; e += 256) {
            int p = pairs[e];
            int pos = atomicAdd(&curL[p & 255], 1);
            col[bstart + pos] = ((unsigned int)p) >> 8;
        }
    }
}

// ---------- MFMA bf16 GEMM (fp32 A, bf16 pre-transposed W in L2): ----------
// out = bf16(A @ W + bias); also emits the dropout bitmask for its 64 rows.
// B-fragments read DIRECTLY from w12b[c*128+k] (32KB, L2-resident).
// du is a single-use stream -> nontemporal loads (don't evict x/h1b from L2).
template <int NCOL>
__global__ __launch_bounds__(256) void k_gemm_mfma(const float* __restrict__ A,
                                                   const unsigned short* __restrict__ Wb,
                                                   const float* __restrict__ bias,
                                                   const float* __restrict__ du,
                                                   unsigned int* __restrict__ dmask,
                                                   unsigned short* __restrict__ out, int M) {
    constexpr int KP = 136;
    __shared__ unsigned short As[64 * KP];

    const int tid = threadIdx.x;
    const int row0 = blockIdx.x * 64;

    for (int f = tid; f < 2048; f += 256) {
        int r = f >> 5, c4 = f & 31;
        int gr = row0 + r;
        float4 v = make_float4(0.f, 0.f, 0.f, 0.f);
        if (gr < M) v = *(const float4*)(A + (size_t)gr * 128 + c4 * 4);
        ushort4 b;
        b.x = f2bf(v.x); b.y = f2bf(v.y); b.z = f2bf(v.z); b.w = f2bf(v.w);
        *(ushort4*)(&As[r * KP + c4 * 4]) = b;
    }
    // fused dropout-bitmask: thread t -> row (t>>2), word (t&3)
    if (dmask) {
        const int gr = row0 + (tid >> 2), w = tid & 3;
        if (gr < M) {
            const float* p = du + (size_t)gr * 128 + w * 32;
            unsigned int m = 0;
#pragma unroll
            for (int jj = 0; jj < 8; ++jj) {
                const float vx = __builtin_nontemporal_load(p + jj * 4 + 0);
                const float vy = __builtin_nontemporal_load(p + jj * 4 + 1);
                const float vz = __builtin_nontemporal_load(p + jj * 4 + 2);
                const float vw = __builtin_nontemporal_load(p + jj * 4 + 3);
                m |= (vx >= 0.5f ? 1u : 0u) << (jj * 4 + 0);
                m |= (vy >= 0.5f ? 1u : 0u) << (jj * 4 + 1);
                m |= (vz >= 0.5f ? 1u : 0u) << (jj * 4 + 2);
                m |= (vw >= 0.5f ? 1u : 0u) << (jj * 4 + 3);
            }
            dmask[gr * 4 + w] = m;
        }
    }
    __syncthreads();

    const int wave = tid >> 6, lane = tid & 63;
    const int quad = lane >> 4, l16 = lane & 15;
    constexpr int CT = (NCOL == 128) ? 2 : 1;
    const int col0 = wave * 16 * CT;

    f32x4 acc[4][CT];
#pragma unroll
    for (int rt = 0; rt < 4; ++rt)
#pragma unroll
        for (int ct = 0; ct < CT; ++ct) acc[rt][ct] = 0.f;

#pragma unroll
    for (int ks = 0; ks < 4; ++ks) {
        const int kbase = ks * 32 + quad * 8;
        bf16x8 bfr[CT];
#pragma unroll
        for (int ct = 0; ct < CT; ++ct)
            bfr[ct] = *(const bf16x8*)(&Wb[(size_t)(col0 + ct * 16 + l16) * 128 + kbase]);
#pragma unroll
        for (int rt = 0; rt < 4; ++rt) {
            bf16x8 afr = *(const bf16x8*)(&As[(rt * 16 + l16) * KP + kbase]);
#pragma unroll
            for (int ct = 0; ct < CT; ++ct)
                acc[rt][ct] = __builtin_amdgcn_mfma_f32_16x16x32_bf16(afr, bfr[ct], acc[rt][ct], 0, 0, 0);
        }
    }

#pragma unroll
    for (int rt = 0; rt < 4; ++rt)
#pragma unroll
        for (int ct = 0; ct < CT; ++ct) {
            const int c = col0 + ct * 16 + l16;
            const float bv = bias ? bias[c] : 0.f;
#pragma unroll
            for (int reg = 0; reg < 4; ++reg) {
                const int gr = row0 + rt * 16 + quad * 4 + reg;
                if (gr < M) out[(size_t)gr * NCOL + c] = f2bf(acc[rt][ct][reg] + bv);
            }
        }
}

// ---------- CSR gather (bf16 input rows, fp32 accumulate) ----------
__device__ __forceinline__ void bfacc(uint4 v, float d, float* acc) {
    acc[0] = fmaf(d, __uint_as_float(v.x << 16),        acc[0]);
    acc[1] = fmaf(d, __uint_as_float(v.x & 0xffff0000u), acc[1]);
    acc[2] = fmaf(d, __uint_as_float(v.y << 16),        acc[2]);
    acc[3] = fmaf(d, __uint_as_float(v.y & 0xffff0000u), acc[3]);
    acc[4] = fmaf(d, __uint_as_float(v.z << 16),        acc[4]);
    acc[5] = fmaf(d, __uint_as_float(v.z & 0xffff0000u), acc[5]);
    acc[6] = fmaf(d, __uint_as_float(v.w << 16),        acc[6]);
    acc[7] = fmaf(d, __uint_as_float(v.w & 0xffff0000u), acc[7]);
}

// FUSED: conv1 aggregation + dropout/relu + conv2 GEMM (proven 66.5us form).
// Node-range parameterized (base..n) so it can be launched as two half-N
// dispatches: each ~33us, which lets the hidden kernels surface in the
// profiler's top-5 (diagnostic for the next round; zero perf cost).
__global__ __launch_bounds__(256) void k_gather_gemm2(const unsigned short* __restrict__ h,
                                                      const int* __restrict__ row_start,
                                                      const int* __restrict__ col,
                                                      const float* __restrict__ dis,
                                                      const float* __restrict__ bias,
                                                      const unsigned int* __restrict__ dmask,
                                                      const unsigned short* __restrict__ w2b,
                                                      unsigned short* __restrict__ h2b,
                                                      int base, int n) {
    constexpr int KP = 136;
    __shared__ unsigned short As[16 * KP];
    __shared__ unsigned short Wt[64 * KP];
    const int tid = threadIdx.x;
    const int node0 = base + blockIdx.x * 16;
    const int node = node0 + (tid >> 4);
    const int l = tid & 15;
    const int coff = l * 8;

    for (int f = tid * 4; f < 8192; f += 1024) {
        const int c = f >> 7, k = f & 127;
        *(ushort4*)(&Wt[c * KP + k]) = *(const ushort4*)(&w2b[f]);
    }

    float r[8];
    if (node < n) {
        const float dn = dis[node];
        const unsigned int mword = dmask[node * 4 + (l >> 2)];
        const unsigned int mbyte = (mword >> ((l & 3) * 8)) & 0xffu;
        float acc[8];
        {
            uint4 v = *(const uint4*)(h + (size_t)node * 128 + coff);
#pragma unroll
            for (int q = 0; q < 8; ++q) acc[q] = 0.f;
            bfacc(v, dn, acc);
        }
        const int beg = row_start[node], end = row_start[node + 1];
        int j = beg;
        for (; j + 3 < end; j += 4) {
            const int s0 = col[j], s1 = col[j + 1], s2 = col[j + 2], s3 = col[j + 3];
            const float d0 = dis[s0], d1 = dis[s1], d2 = dis[s2], d3 = dis[s3];
            const uint4 v0 = *(const uint4*)(h + (size_t)s0 * 128 + coff);
            const uint4 v1 = *(const uint4*)(h + (size_t)s1 * 128 + coff);
            const uint4 v2 = *(const uint4*)(h + (size_t)s2 * 128 + coff);
            const uint4 v3 = *(const uint4*)(h + (size_t)s3 * 128 + coff);
            bfacc(v0, d0, acc);
            bfacc(v1, d1, acc);
            bfacc(v2, d2, acc);
            bfacc(v3, d3, acc);
        }
        for (; j < end; ++j) {
            const int s0 = col[j];
            const float d0 = dis[s0];
            const uint4 v0 = *(const uint4*)(h + (size_t)s0 * 128 + coff);
            bfacc(v0, d0, acc);
        }
        const float4 b0 = *(const float4*)(bias + coff);
        const float4 b1 = *(const float4*)(bias + coff + 4);
        r[0] = fmaf(dn, acc[0], b0.x); r[1] = fmaf(dn, acc[1], b0.y);
        r[2] = fmaf(dn, acc[2], b0.z); r[3] = fmaf(dn, acc[3], b0.w);
        r[4] = fmaf(dn, acc[4], b1.x); r[5] = fmaf(dn, acc[5], b1.y);
        r[6] = fmaf(dn, acc[6], b1.z); r[7] = fmaf(dn, acc[7], b1.w);
        // dropout p=0.5 (keep-bit from dmask, x2) then relu; power-of-2 scale
        // commutes with RNE-to-bf16 -> bit-identical to the unfused path.
#pragma unroll
        for (int q = 0; q < 8; ++q)
            r[q] = ((mbyte >> q) & 1u) ? 2.f * fmaxf(r[q], 0.f) : 0.f;
    } else {
#pragma unroll
        for (int q = 0; q < 8; ++q) r[q] = 0.f;
    }
    ushort4 o0, o1;
    o0.x = f2bf(r[0]); o0.y = f2bf(r[1]); o0.z = f2bf(r[2]); o0.w = f2bf(r[3]);
    o1.x = f2bf(r[4]); o1.y = f2bf(r[5]); o1.z = f2bf(r[6]); o1.w = f2bf(r[7]);
    *(ushort4*)(&As[(tid >> 4) * KP + coff]) = o0;
    *(ushort4*)(&As[(tid >> 4) * KP + coff + 4]) = o1;
    __syncthreads();

    const int wave = tid >> 6, lane = tid & 63;
    const int quad = lane >> 4, l16 = lane & 15;
    const int c0 = wave * 16;
    f32x4 a2 = 0.f;
#pragma unroll
    for (int ks = 0; ks < 4; ++ks) {
        const int kbase = ks * 32 + quad * 8;
        bf16x8 afr = *(const bf16x8*)(&As[l16 * KP + kbase]);
        bf16x8 bfr = *(const bf16x8*)(&Wt[(c0 + l16) * KP + kbase]);
        a2 = __builtin_amdgcn_mfma_f32_16x16x32_bf16(afr, bfr, a2, 0, 0, 0);
    }
#pragma unroll
    for (int reg = 0; reg < 4; ++reg) {
        const int gr = node0 + quad * 4 + reg;
        if (gr < n) h2b[(size_t)gr * 64 + c0 + l16] = f2bf(a2[reg]);
    }
}

// conv2 gather fused with pooling. 8 lanes/node, 32 nodes/block; uniform
// blocks emit one partial row, no hot atomics.
__global__ __launch_bounds__(256) void k_gather_pool(const unsigned short* __restrict__ h,
                                                     const int* __restrict__ row_start,
                                                     const int* __restrict__ col,
                                                     const float* __restrict__ dis,
                                                     const float* __restrict__ bias,
                                                     const int* __restrict__ batch,
                                                     float* __restrict__ partial,
                                                     int* __restrict__ bgid,
                                                     int* __restrict__ bvcnt,
                                                     float* __restrict__ sums,
                                                     float* __restrict__ cnt, int n) {
    __shared__ float bsum[4][64];
    __shared__ int sh_gfirst, sh_uni;
    const int tid = threadIdx.x;
    const int node = (blockIdx.x * 256 + tid) >> 3;
    const int l = tid & 7;
    const int coff = l * 8;
    const bool valid = node < n;
    const int node0 = blockIdx.x * 32;

    if (tid == 0) { sh_gfirst = batch[node0]; sh_uni = 1; }
    __syncthreads();
    const int gfirst = sh_gfirst;

    float r[8];
    int g = gfirst;
    if (valid) {
        const float dn = dis[node];
        g = batch[node];
        float acc[8];
        {
            uint4 v = *(const uint4*)(h + (size_t)node * 64 + coff);
#pragma unroll
            for (int q = 0; q < 8; ++q) acc[q] = 0.f;
            bfacc(v, dn, acc);
        }
        const int beg = row_start[node], end = row_start[node + 1];
        int j = beg;
        for (; j + 3 < end; j += 4) {
            const int s0 = col[j], s1 = col[j + 1], s2 = col[j + 2], s3 = col[j + 3];
            const float d0 = dis[s0], d1 = dis[s1], d2 = dis[s2], d3 = dis[s3];
            const uint4 v0 = *(const uint4*)(h + (size_t)s0 * 64 + coff);
            const uint4 v1 = *(const uint4*)(h + (size_t)s1 * 64 + coff);
            const uint4 v2 = *(const uint4*)(h + (size_t)s2 * 64 + coff);
            const uint4 v3 = *(const uint4*)(h + (size_t)s3 * 64 + coff);
            bfacc(v0, d0, acc);
            bfacc(v1, d1, acc);
            bfacc(v2, d2, acc);
            bfacc(v3, d3, acc);
        }
        for (; j < end; ++j) {
            const int s0 = col[j];
            const float d0 = dis[s0];
            const uint4 v0 = *(const uint4*)(h + (size_t)s0 * 64 + coff);
            bfacc(v0, d0, acc);
        }
        const float4 b0 = *(const float4*)(bias + coff);
        const float4 b1 = *(const float4*)(bias + coff + 4);
        r[0] = fmaf(dn, acc[0], b0.x); r[1] = fmaf(dn, acc[1], b0.y);
        r[2] = fmaf(dn, acc[2], b0.z); r[3] = fmaf(dn, acc[3], b0.w);
        r[4] = fmaf(dn, acc[4], b1.x); r[5] = fmaf(dn, acc[5], b1.y);
        r[6] = fmaf(dn, acc[6], b1.z); r[7] = fmaf(dn, acc[7], b1.w);
    } else {
#pragma unroll
        for (int q = 0; q < 8; ++q) r[q] = 0.f;
    }

    if (valid && g != gfirst) atomicAnd(&sh_uni, 0);
    __syncthreads();

    if (sh_uni) {
        // whole block one graph: wave xor-reduce -> LDS -> one partial row
#pragma unroll
        for (int q = 0; q < 8; ++q) {
            r[q] += __shfl_xor(r[q], 8);
            r[q] += __shfl_xor(r[q], 16);
            r[q] += __shfl_xor(r[q], 32);
        }
        const int wave = tid >> 6, lane = tid & 63;
        if (lane < 8) {
#pragma unroll
            for (int q = 0; q < 8; ++q) bsum[wave][lane * 8 + q] = r[q];
        }
        __syncthreads();
        if (tid < 64)
            partial[(size_t)blockIdx.x * 64 + tid] =
                bsum[0][tid] + bsum[1][tid] + bsum[2][tid] + bsum[3][tid];
        if (tid == 0) {
            bgid[blockIdx.x] = gfirst;
            bvcnt[blockIdx.x] = min(n - node0, 32);
        }
    } else {
        if (tid == 0) bgid[blockIdx.x] = -1;
        const int g0 = __shfl(g, 0);
        const bool wuni = __all(valid && (g == g0));
        if (wuni) {
#pragma unroll
            for (int q = 0; q < 8; ++q) {
                r[q] += __shfl_xor(r[q], 8);
                r[q] += __shfl_xor(r[q], 16);
                r[q] += __shfl_xor(r[q], 32);
            }
            const int lane = tid & 63;
            if (lane < 8) {
#pragma unroll
                for (int q = 0; q < 8; ++q) atomAddF(&sums[g0 * 64 + lane * 8 + q], r[q]);
                if (lane == 0) atomAddF(&cnt[g0], 8.0f);
            }
        } else if (valid) {
#pragma unroll
            for (int q = 0; q < 8; ++q) atomAddF(&sums[g * 64 + coff + q], r[q]);
            if (l == 0) atomAddF(&cnt[g], 1.0f);
        }
    }
}

// Stage 2: run-accumulate the (sorted-by-construction) per-block partial rows.
__global__ __launch_bounds__(256) void k_pool2(const float* __restrict__ partial,
                                               const int* __restrict__ bgid,
                                               const int* __restrict__ bvcnt,
                                               float* __restrict__ sums,
                                               float* __restrict__ cnt, int nb) {
    const int grp = (blockIdx.x * 256 + (int)threadIdx.x) >> 6;
    const int f = threadIdx.x & 63;
    const int ngroups = gridDim.x * 4;
    const int per = (nb + ngroups - 1) / ngroups;
    const int start = grp * per, end = min(nb, start + per);
    if (start >= end) return;
    int cg = -1;
    float acc = 0.f;
    int vc = 0;
    for (int b = start; b < end; ++b) {
        const int g = bgid[b];
        if (g != cg) {
            if (cg >= 0) {
                atomAddF(&sums[cg * 64 + f], acc);
                if (f == 0) atomAddF(&cnt[cg], (float)vc);
            }
            acc = 0.f; vc = 0; cg = g;
        }
        if (g >= 0) {
            acc += partial[(size_t)b * 64 + f];
            vc += bvcnt[b];
        }
    }
    if (cg >= 0) {
        atomAddF(&sums[cg * 64 + f], acc);
        if (f == 0) atomAddF(&cnt[cg], (float)vc);
    }
}

// ---------- final ----------
__global__ __launch_bounds__(64) void k_final(const float* __restrict__ sums,
                                              const float* __restrict__ cnt,
                                              const float* __restrict__ w,
                                              const float* __restrict__ b,
                                              float* __restrict__ out) {
    int g = blockIdx.x, f = threadIdx.x;
    float c = fmaxf(cnt[g], 1.0f);
    float p = sums[g * 64 + f] / c;
#pragma unroll
    for (int cls = 0; cls < NCLS; ++cls) {
        float v = p * w[f * 10 + cls];
#pragma unroll
        for (int o = 32; o > 0; o >>= 1) v += __shfl_down(v, o);
        if (f == 0) out[g * 10 + cls] = v + b[cls];
    }
}

extern "C" void kernel_launch(void* const* d_in, const int* in_sizes, int n_in,
                              void* d_out, int out_size, void* d_ws, size_t ws_size,
                              hipStream_t stream) {
    const float* x       = (const float*)d_in[0];
    const int*   ei      = (const int*)d_in[1];
    const int*   batch   = (const int*)d_in[2];
    const float* drop_u  = (const float*)d_in[4];
    const float* lin1_w  = (const float*)d_in[5];
    const float* lin1_b  = (const float*)d_in[6];
    const float* conv1_w = (const float*)d_in[7];
    const float* conv1_b = (const float*)d_in[8];
    const float* conv2_w = (const float*)d_in[9];
    const float* conv2_b = (const float*)d_in[10];
    const float* lin2_w  = (const float*)d_in[11];
    const float* lin2_b  = (const float*)d_in[12];
    float* out = (float*)d_out;

    const int N = in_sizes[0] / DIN;        // 100000
    const int E = in_sizes[1] / 2;          // 1600000
    const int* src = ei;
    const int* dst = ei + E;

    const int nbkt = (N + 255) >> 8;        // 391
    const int M = nbkt * NBLK;              // bh scan length
    const int nbGP = (int)(((size_t)N * 8 + 255) / 256);   // gather_pool blocks (3125)

    // workspace layout (float units) — identical footprint to passing round 10.
    float* ws    = (float*)d_ws;
    float* out1  = ws;                                   // N*128 region (h2b + w2b live here)
    unsigned short* h1b = (unsigned short*)(ws + (size_t)N * 128);   // N*128 bf16
    float* dis   = ws + (size_t)N * 128 + (size_t)N * 64;            // N
    float* W12r  = dis + N;                              // 16384 floats (w12b lives here: 32KB)
    float* c1pb  = W12r + 16384;                         // 128
    float* sums  = c1pb + 128;                           // 8192
    float* cntp  = sums + NGRAPH * 64;                   // 128
    int*   row_start = (int*)(cntp + NGRAPH);            // N+2 (padded)
    int*   part  = row_start + N + 2;                    // 256
    int*   bh    = part + 256;                           // NBKT_MAX*NBLK+2
    int*   col   = bh + NBKT_MAX * NBLK + 2;             // E
    int*   pairs = col + E;                              // E (packed src<<8|dst&255)
    float* partial = (float*)(pairs + E);                // nbGP*64
    int*   bgid  = (int*)(partial + (size_t)nbGP * 64);  // nbGP
    int*   bvcnt = bgid + nbGP;                          // nbGP
    unsigned int* dmask = (unsigned int*)pairs;          // N*4 words — ALIASES pairs (dead after csr_local)
    unsigned short* w12b = (unsigned short*)W12r;        // 16384 bf16 [c][k] (32KB)
    unsigned short* h2b = (unsigned short*)out1;         // N*64 bf16 (first N*32 floats of out1)
    unsigned short* w2b = (unsigned short*)(out1 + (size_t)N * 64);  // 8192 bf16 (16KB, inside out1)

    // radix pass 1 + all weight prep in one launch (disjoint block ranges)
    k_bhist<<<NBLK + 66, 256, 0, stream>>>(dst, bh, E, nbkt, sums, NGRAPH * 64 + NGRAPH,
                                           lin1_w, lin1_b, conv1_w, conv2_w, w12b, c1pb, w2b);
    const int scanB = (M + SCAN_CHUNK - 1) / SCAN_CHUNK;          // 98 <= 256
    k_scan_part<<<scanB, 256, 0, stream>>>(bh, part, M);
    k_scan_mid<<<1, 256, 0, stream>>>(part, bh, scanB, M);        // also bh[M] = E
    k_scan_fin2<<<scanB, 256, 0, stream>>>(bh, part, bh, M);
    k_partition<<<NBLK, 256, 0, stream>>>(src, dst, bh, pairs, E, nbkt);
    k_csr_local<<<nbkt, 256, 0, stream>>>(pairs, bh, row_start, dis, col, N);

    // h1b = bf16(x @ W12 + c1pb) (MFMA, B direct from L2) + dropout bitmask
    const int gemmGrid = (N + 63) / 64;
    k_gemm_mfma<128><<<gemmGrid, 256, 0, stream>>>(x, w12b, c1pb, drop_u, dmask, h1b, N);

    // FUSED conv1 aggregation + dropout/relu + conv2 GEMM -> h2b
    // (two half-N dispatches: diagnostic split so hidden kernels surface in top-5)
    const int nh = ((N / 2) + 15) & ~15;                 // 50000 (multiple of 16)
    k_gather_gemm2<<<nh / 16, 256, 0, stream>>>(h1b, row_start, col, dis, conv1_b,
                                                dmask, w2b, h2b, 0, nh);
    k_gather_gemm2<<<(N - nh + 15) / 16, 256, 0, stream>>>(h1b, row_start, col, dis, conv1_b,
                                                           dmask, w2b, h2b, nh, N);

    // conv2 aggregation fused with block-partial pooling (no hot atomics)
    k_gather_pool<<<nbGP, 256, 0, stream>>>(h2b, row_start, col, dis, conv2_b, batch,
                                            partial, bgid, bvcnt, sums, cntp, N);
    k_pool2<<<16, 256, 0, stream>>>(partial, bgid, bvcnt, sums, cntp, nbGP);

    // classifier
    k_final<<<NGRAPH, 64, 0, stream>>>(sums, cntp, lin2_w, lin2_b, out);
}

// Round 12
// 385.367 us; speedup vs baseline: 1.0103x; 1.0103x over previous
//
#include <hip/hip_runtime.h>
#include <hip/hip_bf16.h>

// Problem constants (fixed by the reference file)
#define DIN   128
#define HID2  64
#define NCLS  10
#define NGRAPH 128
#define SCAN_CHUNK 1024
#define NBLK 256          // blocks in bhist/partition (edge assignment must match)
#define NBKT_MAX 512      // max buckets (nodes/256)
#define CAP 6144          // LDS src-staging capacity per bucket (mean 4096, +32 sigma)
#define EPB 6400          // max edges per partition block = ceil(E/65536)*256 (E=1.6M)

typedef __attribute__((ext_vector_type(8))) short bf16x8;
typedef __attribute__((ext_vector_type(4))) float f32x4;

__device__ __forceinline__ void atomAddF(float* p, float v) {
    unsafeAtomicAdd(p, v);
}

// float -> bf16 (round-to-nearest-even), finite inputs.
__device__ __forceinline__ unsigned short f2bf(float f) {
    unsigned int u = __float_as_uint(f);
    u += 0x7fffu + ((u >> 16) & 1u);
    return (unsigned short)(u >> 16);
}

// ---------- combined prep + radix pass 1 ----------
// Blocks [0, NBLK): per-(bucket,block) histogram bh[bkt*NBLK + blk];
//   block 0 also zeroes the pooling accumulators.
// Blocks [NBLK, NBLK+65): w12b = bf16((lin1_w @ conv1_w)^T) (2 rows/block)
//   and c1preb = lin1_b @ conv1_w. w12b is stored [c][k] so the GEMM reads
//   B-fragments directly from L2 (no LDS tile, no bank conflicts).
// Block NBLK+65: w2b = bf16(conv2_w^T) for the fused gather+GEMM.
__global__ __launch_bounds__(256) void k_bhist(const int* __restrict__ dst,
                                               int* __restrict__ bh, int E, int nbkt,
                                               float* __restrict__ zbuf, int zn,
                                               const float* __restrict__ lw,
                                               const float* __restrict__ lb,
                                               const float* __restrict__ cw,
                                               const float* __restrict__ cw2,
                                               unsigned short* __restrict__ w12b,
                                               float* __restrict__ c1preb,
                                               unsigned short* __restrict__ w2b) {
    const int tid = threadIdx.x;
    if (blockIdx.x >= NBLK) {
        const int bi = blockIdx.x - NBLK;
        if (bi == 65) {
            // w2b[c*128+k] = bf16(cw2[k*64+c]); 32KB source, L2-hot
            for (int f = tid; f < 8192; f += 256) w2b[f] = f2bf(cw2[(f & 127) * 64 + (f >> 7)]);
        } else {
            const int i = bi * 2 + (tid >> 7);   // 0..129 (129 skipped)
            if (i <= 128) {
                const int j = tid & 127;
                const float* arow = (i < 128) ? (lw + i * 128) : lb;
                float acc = 0.f;
#pragma unroll 8
                for (int k = 0; k < 128; ++k) acc += arow[k] * cw[k * 128 + j];
                if (i < 128) w12b[j * 128 + i] = f2bf(acc);   // transposed bf16
                else         c1preb[j] = acc;
            }
        }
        return;
    }
    __shared__ int lh[NBKT_MAX];
    if (blockIdx.x == 0)
        for (int i = tid; i < zn; i += 256) zbuf[i] = 0.f;
    for (int i = tid; i < nbkt; i += 256) lh[i] = 0;
    __syncthreads();
    for (int e = blockIdx.x * 256 + tid; e < E; e += NBLK * 256)
        atomicAdd(&lh[__builtin_nontemporal_load(dst + e) >> 8], 1);
    __syncthreads();
    for (int i = tid; i < nbkt; i += 256) bh[i * NBLK + blockIdx.x] = lh[i];
}

// --- 3-phase parallel exclusive scan (generic length; used on bh in-place) ---
__global__ __launch_bounds__(256) void k_scan_part(const int* __restrict__ cnt,
                                                   int* __restrict__ part, int n) {
    int base = blockIdx.x * SCAN_CHUNK + threadIdx.x * 4;
    int s = 0;
#pragma unroll
    for (int j = 0; j < 4; ++j) { int i = base + j; if (i < n) s += cnt[i]; }
#pragma unroll
    for (int o = 32; o > 0; o >>= 1) s += __shfl_down(s, o);
    __shared__ int wsum[4];
    if ((threadIdx.x & 63) == 0) wsum[threadIdx.x >> 6] = s;
    __syncthreads();
    if (threadIdx.x == 0) part[blockIdx.x] = wsum[0] + wsum[1] + wsum[2] + wsum[3];
}
__global__ __launch_bounds__(256) void k_scan_mid(int* __restrict__ part,
                                                  int* __restrict__ total_out,
                                                  int B, int n) {
    __shared__ int sh[256];
    int t = threadIdx.x;
    int v = (t < B) ? part[t] : 0;
    sh[t] = v;
    __syncthreads();
    for (int off = 1; off < 256; off <<= 1) {
        int u = (t >= off) ? sh[t - off] : 0;
        __syncthreads();
        sh[t] += u;
        __syncthreads();
    }
    if (t < B) part[t] = sh[t] - v;
    if (t == 255) total_out[n] = sh[255];
}
// in-place-safe (out may alias cnt: all reads precede a barrier before writes)
__global__ __launch_bounds__(256) void k_scan_fin2(const int* cnt,
                                                   const int* __restrict__ part,
                                                   int* out, int n) {
    __shared__ int sh[256];
    int t = threadIdx.x;
    int base = blockIdx.x * SCAN_CHUNK + t * 4;
    int c[4]; int s = 0;
#pragma unroll
    for (int j = 0; j < 4; ++j) { int i = base + j; c[j] = (i < n) ? cnt[i] : 0; s += c[j]; }
    sh[t] = s;
    __syncthreads();
    for (int off = 1; off < 256; off <<= 1) {
        int u = (t >= off) ? sh[t - off] : 0;
        __syncthreads();
        sh[t] += u;
        __syncthreads();
    }
    int excl = part[blockIdx.x] + sh[t] - s;
#pragma unroll
    for (int j = 0; j < 4; ++j) {
        int i = base + j;
        if (i < n) out[i] = excl;
        excl += c[j];
    }
}

// Pass 2: in-LDS counting sort, then COALESCED write-out of packed
// (src<<8 | dst&255) edges. Edge->block assignment identical to k_bhist.
__global__ __launch_bounds__(256) void k_partition(const int* __restrict__ src,
                                                   const int* __restrict__ dst,
                                                   const int* __restrict__ bh,
                                                   int* __restrict__ pairs, int E, int nbkt) {
    __shared__ int lh[NBKT_MAX];
    __shared__ int lscan[NBKT_MAX + 2];
    __shared__ int gofs[NBKT_MAX];
    __shared__ int lcur[NBKT_MAX];
    __shared__ int scanw[256];
    __shared__ int lbuf[EPB];
    const int tid = threadIdx.x;
    const int b = blockIdx.x;

    for (int i = tid; i < NBKT_MAX; i += 256) lh[i] = 0;
    __syncthreads();
    for (int e = b * 256 + tid; e < E; e += NBLK * 256)
        atomicAdd(&lh[__builtin_nontemporal_load(dst + e) >> 8], 1);
    __syncthreads();
    const int a0 = lh[2 * tid], a1 = lh[2 * tid + 1];
    const int ps = a0 + a1;
    scanw[tid] = ps;
    __syncthreads();
    for (int off = 1; off < 256; off <<= 1) {
        int u = (tid >= off) ? scanw[tid - off] : 0;
        __syncthreads();
        scanw[tid] += u;
        __syncthreads();
    }
    const int ex = scanw[tid] - ps;
    lscan[2 * tid] = ex;
    lscan[2 * tid + 1] = ex + a0;
    if (tid == 255) lscan[512] = scanw[255];
    __syncthreads();
#pragma unroll
    for (int q = 0; q < 2; ++q) {
        const int k = 2 * tid + q;
        lcur[k] = lscan[k];
        if (k < nbkt) gofs[k] = bh[k * NBLK + b] - lscan[k];
    }
    __syncthreads();
    for (int e = b * 256 + tid; e < E; e += NBLK * 256) {
        const int d = __builtin_nontemporal_load(dst + e);
        const int s = __builtin_nontemporal_load(src + e);
        const int lpos = atomicAdd(&lcur[d >> 8], 1);
        lbuf[lpos] = (s << 8) | (d & 255);
    }
    __syncthreads();
    const int cnt = lscan[512];
    for (int i = tid; i < cnt; i += 256) {
        int lo = 0, hi = nbkt;
        while (hi - lo > 1) {
            const int mid = (lo + hi) >> 1;
            if (lscan[mid] <= i) lo = mid; else hi = mid;
        }
        pairs[gofs[lo] + i] = lbuf[i];
    }
}

// Pass 3: one block per bucket. In-LDS degree count + scan + scatter, then
// coalesced single-touch streams: row_start, dis, col. No global atomics.
__global__ __launch_bounds__(256) void k_csr_local(const int* __restrict__ pairs,
                                                   const int* __restrict__ bh,
                                                   int* __restrict__ row_start,
                                                   float* __restrict__ dis,
                                                   int* __restrict__ col,
                                                   int N) {
    __shared__ int cntL[256], scanL[256], curL[256];
    __shared__ int srcbuf[CAP];
    const int tid = threadIdx.x;
    const int lo = blockIdx.x << 8;
    const int bstart = bh[blockIdx.x * NBLK];
    const int bend = bh[(blockIdx.x + 1) * NBLK];   // last bucket: bh[nbkt*NBLK] == E
    const int nE = bend - bstart;

    cntL[tid] = 0;
    __syncthreads();
    for (int e = bstart + tid; e < bend; e += 256)
        atomicAdd(&cntL[pairs[e] & 255], 1);
    __syncthreads();
    const int deg = cntL[tid];
    scanL[tid] = deg;
    __syncthreads();
    for (int off = 1; off < 256; off <<= 1) {
        int u = (tid >= off) ? scanL[tid - off] : 0;
        __syncthreads();
        scanL[tid] += u;
        __syncthreads();
    }
    const int excl = scanL[tid] - deg;
    curL[tid] = excl;
    const int node = lo + tid;
    if (node < N) {
        row_start[node] = bstart + excl;
        dis[node] = rsqrtf((float)(deg + 1));   // +1 self-loop
    } else if (node == N) {
        row_start[N] = bend;                    // == E (only last bucket reaches here)
    }
    __syncthreads();
    if (nE <= CAP) {
        for (int e = bstart + tid; e < bend; e += 256) {
            int p = pairs[e];
            int pos = atomicAdd(&curL[p & 255], 1);
            srcbuf[pos] = ((unsigned int)p) >> 8;
        }
        __syncthreads();
        for (int i = tid; i < nE; i += 256)
            col[bstart + i] = srcbuf[i];
    } else {  // overflow fallback (statistically never for random graphs)
        for (int e = bstart + tid; e < bend; e += 256) {
            int p = pairs[e];
            int pos = atomicAdd(&curL[p & 255], 1);
            col[bstart + pos] = ((unsigned int)p) >> 8;
        }
    }
}

// ---------- MFMA bf16 GEMM (fp32 A, bf16 pre-transposed W in L2): ----------
// out = bf16(A @ W + bias); also emits the dropout bitmask for its 64 rows.
// DEEP-PIPELINED staging: all 8 x-float4 AND all 8 du-float4 loads are issued
// into explicit register arrays BEFORE any use — ~16 loads in flight/thread.
// (r11 PMC: VGPR=52 allocation left the kernel latency-bound at 1.6 TB/s,
//  VALUBusy 8.6%; trading VGPRs for MLP is the fix for a streaming kernel.)
template <int NCOL>
__global__ __launch_bounds__(256) void k_gemm_mfma(const float* __restrict__ A,
                                                   const unsigned short* __restrict__ Wb,
                                                   const float* __restrict__ bias,
                                                   const float* __restrict__ du,
                                                   unsigned int* __restrict__ dmask,
                                                   unsigned short* __restrict__ out, int M) {
    constexpr int KP = 136;
    __shared__ unsigned short As[64 * KP];

    const int tid = threadIdx.x;
    const int row0 = blockIdx.x * 64;

    // issue all x loads
    float4 xv[8];
#pragma unroll
    for (int j = 0; j < 8; ++j) {
        const int f = tid + j * 256;
        const int r = f >> 5, c4 = f & 31;
        const int gr = row0 + r;
        xv[j] = make_float4(0.f, 0.f, 0.f, 0.f);
        if (gr < M) xv[j] = *(const float4*)(A + (size_t)gr * 128 + c4 * 4);
    }
    // issue all du loads (thread t -> row (t>>2), word (t&3))
    const int gmr = row0 + (tid >> 2), wq = tid & 3;
    const bool mok = dmask && (gmr < M);
    float4 uv[8];
#pragma unroll
    for (int jj = 0; jj < 8; ++jj)
        uv[jj] = mok ? *(const float4*)(du + (size_t)gmr * 128 + wq * 32 + jj * 4)
                     : make_float4(0.f, 0.f, 0.f, 0.f);
    // consume: LDS stores + bitmask
#pragma unroll
    for (int j = 0; j < 8; ++j) {
        const int f = tid + j * 256;
        const int r = f >> 5, c4 = f & 31;
        ushort4 b;
        b.x = f2bf(xv[j].x); b.y = f2bf(xv[j].y); b.z = f2bf(xv[j].z); b.w = f2bf(xv[j].w);
        *(ushort4*)(&As[r * KP + c4 * 4]) = b;
    }
    if (mok) {
        unsigned int m = 0;
#pragma unroll
        for (int jj = 0; jj < 8; ++jj) {
            m |= (uv[jj].x >= 0.5f ? 1u : 0u) << (jj * 4 + 0);
            m |= (uv[jj].y >= 0.5f ? 1u : 0u) << (jj * 4 + 1);
            m |= (uv[jj].z >= 0.5f ? 1u : 0u) << (jj * 4 + 2);
            m |= (uv[jj].w >= 0.5f ? 1u : 0u) << (jj * 4 + 3);
        }
        dmask[gmr * 4 + wq] = m;
    }
    __syncthreads();

    const int wave = tid >> 6, lane = tid & 63;
    const int quad = lane >> 4, l16 = lane & 15;
    constexpr int CT = (NCOL == 128) ? 2 : 1;
    const int col0 = wave * 16 * CT;

    f32x4 acc[4][CT];
#pragma unroll
    for (int rt = 0; rt < 4; ++rt)
#pragma unroll
        for (int ct = 0; ct < CT; ++ct) acc[rt][ct] = 0.f;

#pragma unroll
    for (int ks = 0; ks < 4; ++ks) {
        const int kbase = ks * 32 + quad * 8;
        bf16x8 bfr[CT];
#pragma unroll
        for (int ct = 0; ct < CT; ++ct)
            bfr[ct] = *(const bf16x8*)(&Wb[(size_t)(col0 + ct * 16 + l16) * 128 + kbase]);
#pragma unroll
        for (int rt = 0; rt < 4; ++rt) {
            bf16x8 afr = *(const bf16x8*)(&As[(rt * 16 + l16) * KP + kbase]);
#pragma unroll
            for (int ct = 0; ct < CT; ++ct)
                acc[rt][ct] = __builtin_amdgcn_mfma_f32_16x16x32_bf16(afr, bfr[ct], acc[rt][ct], 0, 0, 0);
        }
    }

#pragma unroll
    for (int rt = 0; rt < 4; ++rt)
#pragma unroll
        for (int ct = 0; ct < CT; ++ct) {
            const int c = col0 + ct * 16 + l16;
            const float bv = bias ? bias[c] : 0.f;
#pragma unroll
            for (int reg = 0; reg < 4; ++reg) {
                const int gr = row0 + rt * 16 + quad * 4 + reg;
                if (gr < M) out[(size_t)gr * NCOL + c] = f2bf(acc[rt][ct][reg] + bv);
            }
        }
}

// ---------- CSR gather (bf16 input rows, fp32 accumulate) ----------
__device__ __forceinline__ void bfacc(uint4 v, float d, float* acc) {
    acc[0] = fmaf(d, __uint_as_float(v.x << 16),        acc[0]);
    acc[1] = fmaf(d, __uint_as_float(v.x & 0xffff0000u), acc[1]);
    acc[2] = fmaf(d, __uint_as_float(v.y << 16),        acc[2]);
    acc[3] = fmaf(d, __uint_as_float(v.y & 0xffff0000u), acc[3]);
    acc[4] = fmaf(d, __uint_as_float(v.z << 16),        acc[4]);
    acc[5] = fmaf(d, __uint_as_float(v.z & 0xffff0000u), acc[5]);
    acc[6] = fmaf(d, __uint_as_float(v.w << 16),        acc[6]);
    acc[7] = fmaf(d, __uint_as_float(v.w & 0xffff0000u), acc[7]);
}

// FUSED: conv1 aggregation + dropout/relu + conv2 GEMM (proven 66.5us form).
// Node-range parameterized (base..n); launched as two half-N dispatches for
// profiler observability (zero perf cost).
__global__ __launch_bounds__(256) void k_gather_gemm2(const unsigned short* __restrict__ h,
                                                      const int* __restrict__ row_start,
                                                      const int* __restrict__ col,
                                                      const float* __restrict__ dis,
                                                      const float* __restrict__ bias,
                                                      const unsigned int* __restrict__ dmask,
                                                      const unsigned short* __restrict__ w2b,
                                                      unsigned short* __restrict__ h2b,
                                                      int base, int n) {
    constexpr int KP = 136;
    __shared__ unsigned short As[16 * KP];
    __shared__ unsigned short Wt[64 * KP];
    const int tid = threadIdx.x;
    const int node0 = base + blockIdx.x * 16;
    const int node = node0 + (tid >> 4);
    const int l = tid & 15;
    const int coff = l * 8;

    for (int f = tid * 4; f < 8192; f += 1024) {
        const int c = f >> 7, k = f & 127;
        *(ushort4*)(&Wt[c * KP + k]) = *(const ushort4*)(&w2b[f]);
    }

    float r[8];
    if (node < n) {
        const float dn = dis[node];
        const unsigned int mword = dmask[node * 4 + (l >> 2)];
        const unsigned int mbyte = (mword >> ((l & 3) * 8)) & 0xffu;
        float acc[8];
        {
            uint4 v = *(const uint4*)(h + (size_t)node * 128 + coff);
#pragma unroll
            for (int q = 0; q < 8; ++q) acc[q] = 0.f;
            bfacc(v, dn, acc);
        }
        const int beg = row_start[node], end = row_start[node + 1];
        int j = beg;
        for (; j + 3 < end; j += 4) {
            const int s0 = col[j], s1 = col[j + 1], s2 = col[j + 2], s3 = col[j + 3];
            const float d0 = dis[s0], d1 = dis[s1], d2 = dis[s2], d3 = dis[s3];
            const uint4 v0 = *(const uint4*)(h + (size_t)s0 * 128 + coff);
            const uint4 v1 = *(const uint4*)(h + (size_t)s1 * 128 + coff);
            const uint4 v2 = *(const uint4*)(h + (size_t)s2 * 128 + coff);
            const uint4 v3 = *(const uint4*)(h + (size_t)s3 * 128 + coff);
            bfacc(v0, d0, acc);
            bfacc(v1, d1, acc);
            bfacc(v2, d2, acc);
            bfacc(v3, d3, acc);
        }
        for (; j < end; ++j) {
            const int s0 = col[j];
            const float d0 = dis[s0];
            const uint4 v0 = *(const uint4*)(h + (size_t)s0 * 128 + coff);
            bfacc(v0, d0, acc);
        }
        const float4 b0 = *(const float4*)(bias + coff);
        const float4 b1 = *(const float4*)(bias + coff + 4);
        r[0] = fmaf(dn, acc[0], b0.x); r[1] = fmaf(dn, acc[1], b0.y);
        r[2] = fmaf(dn, acc[2], b0.z); r[3] = fmaf(dn, acc[3], b0.w);
        r[4] = fmaf(dn, acc[4], b1.x); r[5] = fmaf(dn, acc[5], b1.y);
        r[6] = fmaf(dn, acc[6], b1.z); r[7] = fmaf(dn, acc[7], b1.w);
        // dropout p=0.5 (keep-bit from dmask, x2) then relu; power-of-2 scale
        // commutes with RNE-to-bf16 -> bit-identical to the unfused path.
#pragma unroll
        for (int q = 0; q < 8; ++q)
            r[q] = ((mbyte >> q) & 1u) ? 2.f * fmaxf(r[q], 0.f) : 0.f;
    } else {
#pragma unroll
        for (int q = 0; q < 8; ++q) r[q] = 0.f;
    }
    ushort4 o0, o1;
    o0.x = f2bf(r[0]); o0.y = f2bf(r[1]); o0.z = f2bf(r[2]); o0.w = f2bf(r[3]);
    o1.x = f2bf(r[4]); o1.y = f2bf(r[5]); o1.z = f2bf(r[6]); o1.w = f2bf(r[7]);
    *(ushort4*)(&As[(tid >> 4) * KP + coff]) = o0;
    *(ushort4*)(&As[(tid >> 4) * KP + coff + 4]) = o1;
    __syncthreads();

    const int wave = tid >> 6, lane = tid & 63;
    const int quad = lane >> 4, l16 = lane & 15;
    const int c0 = wave * 16;
    f32x4 a2 = 0.f;
#pragma unroll
    for (int ks = 0; ks < 4; ++ks) {
        const int kbase = ks * 32 + quad * 8;
        bf16x8 afr = *(const bf16x8*)(&As[l16 * KP + kbase]);
        bf16x8 bfr = *(const bf16x8*)(&Wt[(c0 + l16) * KP + kbase]);
        a2 = __builtin_amdgcn_mfma_f32_16x16x32_bf16(afr, bfr, a2, 0, 0, 0);
    }
#pragma unroll
    for (int reg = 0; reg < 4; ++reg) {
        const int gr = node0 + quad * 4 + reg;
        if (gr < n) h2b[(size_t)gr * 64 + c0 + l16] = f2bf(a2[reg]);
    }
}

// conv2 gather fused with pooling. 8 lanes/node, 32 nodes/block; uniform
// blocks emit one partial row, no hot atomics.
__global__ __launch_bounds__(256) void k_gather_pool(const unsigned short* __restrict__ h,
                                                     const int* __restrict__ row_start,
                                                     const int* __restrict__ col,
                                                     const float* __restrict__ dis,
                                                     const float* __restrict__ bias,
                                                     const int* __restrict__ batch,
                                                     float* __restrict__ partial,
                                                     int* __restrict__ bgid,
                                                     int* __restrict__ bvcnt,
                                                     float* __restrict__ sums,
                                                     float* __restrict__ cnt, int n) {
    __shared__ float bsum[4][64];
    __shared__ int sh_gfirst, sh_uni;
    const int tid = threadIdx.x;
    const int node = (blockIdx.x * 256 + tid) >> 3;
    const int l = tid & 7;
    const int coff = l * 8;
    const bool valid = node < n;
    const int node0 = blockIdx.x * 32;

    if (tid == 0) { sh_gfirst = batch[node0]; sh_uni = 1; }
    __syncthreads();
    const int gfirst = sh_gfirst;

    float r[8];
    int g = gfirst;
    if (valid) {
        const float dn = dis[node];
        g = batch[node];
        float acc[8];
        {
            uint4 v = *(const uint4*)(h + (size_t)node * 64 + coff);
#pragma unroll
            for (int q = 0; q < 8; ++q) acc[q] = 0.f;
            bfacc(v, dn, acc);
        }
        const int beg = row_start[node], end = row_start[node + 1];
        int j = beg;
        for (; j + 3 < end; j += 4) {
            const int s0 = col[j], s1 = col[j + 1], s2 = col[j + 2], s3 = col[j + 3];
            const float d0 = dis[s0], d1 = dis[s1], d2 = dis[s2], d3 = dis[s3];
            const uint4 v0 = *(const uint4*)(h + (size_t)s0 * 64 + coff);
            const uint4 v1 = *(const uint4*)(h + (size_t)s1 * 64 + coff);
            const uint4 v2 = *(const uint4*)(h + (size_t)s2 * 64 + coff);
            const uint4 v3 = *(const uint4*)(h + (size_t)s3 * 64 + coff);
            bfacc(v0, d0, acc);
            bfacc(v1, d1, acc);
            bfacc(v2, d2, acc);
            bfacc(v3, d3, acc);
        }
        for (; j < end; ++j) {
            const int s0 = col[j];
            const float d0 = dis[s0];
            const uint4 v0 = *(const uint4*)(h + (size_t)s0 * 64 + coff);
            bfacc(v0, d0, acc);
        }
        const float4 b0 = *(const float4*)(bias + coff);
        const float4 b1 = *(const float4*)(bias + coff + 4);
        r[0] = fmaf(dn, acc[0], b0.x); r[1] = fmaf(dn, acc[1], b0.y);
        r[2] = fmaf(dn, acc[2], b0.z); r[3] = fmaf(dn, acc[3], b0.w);
        r[4] = fmaf(dn, acc[4], b1.x); r[5] = fmaf(dn, acc[5], b1.y);
        r[6] = fmaf(dn, acc[6], b1.z); r[7] = fmaf(dn, acc[7], b1.w);
    } else {
#pragma unroll
        for (int q = 0; q < 8; ++q) r[q] = 0.f;
    }

    if (valid && g != gfirst) atomicAnd(&sh_uni, 0);
    __syncthreads();

    if (sh_uni) {
        // whole block one graph: wave xor-reduce -> LDS -> one partial row
#pragma unroll
        for (int q = 0; q < 8; ++q) {
            r[q] += __shfl_xor(r[q], 8);
            r[q] += __shfl_xor(r[q], 16);
            r[q] += __shfl_xor(r[q], 32);
        }
        const int wave = tid >> 6, lane = tid & 63;
        if (lane < 8) {
#pragma unroll
            for (int q = 0; q < 8; ++q) bsum[wave][lane * 8 + q] = r[q];
        }
        __syncthreads();
        if (tid < 64)
            partial[(size_t)blockIdx.x * 64 + tid] =
                bsum[0][tid] + bsum[1][tid] + bsum[2][tid] + bsum[3][tid];
        if (tid == 0) {
            bgid[blockIdx.x] = gfirst;
            bvcnt[blockIdx.x] = min(n - node0, 32);
        }
    } else {
        if (tid == 0) bgid[blockIdx.x] = -1;
        const int g0 = __shfl(g, 0);
        const bool wuni = __all(valid && (g == g0));
        if (wuni) {
#pragma unroll
            for (int q = 0; q < 8; ++q) {
                r[q] += __shfl_xor(r[q], 8);
                r[q] += __shfl_xor(r[q], 16);
                r[q] += __shfl_xor(r[q], 32);
            }
            const int lane = tid & 63;
            if (lane < 8) {
#pragma unroll
                for (int q = 0; q < 8; ++q) atomAddF(&sums[g0 * 64 + lane * 8 + q], r[q]);
                if (lane == 0) atomAddF(&cnt[g0], 8.0f);
            }
        } else if (valid) {
#pragma unroll
            for (int q = 0; q < 8; ++q) atomAddF(&sums[g * 64 + coff + q], r[q]);
            if (l == 0) atomAddF(&cnt[g], 1.0f);
        }
    }
}

// Stage 2: run-accumulate the (sorted-by-construction) per-block partial rows.
__global__ __launch_bounds__(256) void k_pool2(const float* __restrict__ partial,
                                               const int* __restrict__ bgid,
                                               const int* __restrict__ bvcnt,
                                               float* __restrict__ sums,
                                               float* __restrict__ cnt, int nb) {
    const int grp = (blockIdx.x * 256 + (int)threadIdx.x) >> 6;
    const int f = threadIdx.x & 63;
    const int ngroups = gridDim.x * 4;
    const int per = (nb + ngroups - 1) / ngroups;
    const int start = grp * per, end = min(nb, start + per);
    if (start >= end) return;
    int cg = -1;
    float acc = 0.f;
    int vc = 0;
    for (int b = start; b < end; ++b) {
        const int g = bgid[b];
        if (g != cg) {
            if (cg >= 0) {
                atomAddF(&sums[cg * 64 + f], acc);
                if (f == 0) atomAddF(&cnt[cg], (float)vc);
            }
            acc = 0.f; vc = 0; cg = g;
        }
        if (g >= 0) {
            acc += partial[(size_t)b * 64 + f];
            vc += bvcnt[b];
        }
    }
    if (cg >= 0) {
        atomAddF(&sums[cg * 64 + f], acc);
        if (f == 0) atomAddF(&cnt[cg], (float)vc);
    }
}

// ---------- final ----------
__global__ __launch_bounds__(64) void k_final(const float* __restrict__ sums,
                                              const float* __restrict__ cnt,
                                              const float* __restrict__ w,
                                              const float* __restrict__ b,
                                              float* __restrict__ out) {
    int g = blockIdx.x, f = threadIdx.x;
    float c = fmaxf(cnt[g], 1.0f);
    float p = sums[g * 64 + f] / c;
#pragma unroll
    for (int cls = 0; cls < NCLS; ++cls) {
        float v = p * w[f * 10 + cls];
#pragma unroll
        for (int o = 32; o > 0; o >>= 1) v += __shfl_down(v, o);
        if (f == 0) out[g * 10 + cls] = v + b[cls];
    }
}

extern "C" void kernel_launch(void* const* d_in, const int* in_sizes, int n_in,
                              void* d_out, int out_size, void* d_ws, size_t ws_size,
                              hipStream_t stream) {
    const float* x       = (const float*)d_in[0];
    const int*   ei      = (const int*)d_in[1];
    const int*   batch   = (const int*)d_in[2];
    const float* drop_u  = (const float*)d_in[4];
    const float* lin1_w  = (const float*)d_in[5];
    const float* lin1_b  = (const float*)d_in[6];
    const float* conv1_w = (const float*)d_in[7];
    const float* conv1_b = (const float*)d_in[8];
    const float* conv2_w = (const float*)d_in[9];
    const float* conv2_b = (const float*)d_in[10];
    const float* lin2_w  = (const float*)d_in[11];
    const float* lin2_b  = (const float*)d_in[12];
    float* out = (float*)d_out;

    const int N = in_sizes[0] / DIN;        // 100000
    const int E = in_sizes[1] / 2;          // 1600000
    const int* src = ei;
    const int* dst = ei + E;

    const int nbkt = (N + 255) >> 8;        // 391
    const int M = nbkt * NBLK;              // bh scan length
    const int nbGP = (int)(((size_t)N * 8 + 255) / 256);   // gather_pool blocks (3125)

    // workspace layout (float units) — identical footprint to passing round 11.
    float* ws    = (float*)d_ws;
    float* out1  = ws;                                   // N*128 region (h2b + w2b live here)
    unsigned short* h1b = (unsigned short*)(ws + (size_t)N * 128);   // N*128 bf16
    float* dis   = ws + (size_t)N * 128 + (size_t)N * 64;            // N
    float* W12r  = dis + N;                              // 16384 floats (w12b lives here: 32KB)
    float* c1pb  = W12r + 16384;                         // 128
    float* sums  = c1pb + 128;                           // 8192
    float* cntp  = sums + NGRAPH * 64;                   // 128
    int*   row_start = (int*)(cntp + NGRAPH);            // N+2 (padded)
    int*   part  = row_start + N + 2;                    // 256
    int*   bh    = part + 256;                           // NBKT_MAX*NBLK+2
    int*   col   = bh + NBKT_MAX * NBLK + 2;             // E
    int*   pairs = col + E;                              // E (packed src<<8|dst&255)
    float* partial = (float*)(pairs + E);                // nbGP*64
    int*   bgid  = (int*)(partial + (size_t)nbGP * 64);  // nbGP
    int*   bvcnt = bgid + nbGP;                          // nbGP
    unsigned int* dmask = (unsigned int*)pairs;          // N*4 words — ALIASES pairs (dead after csr_local)
    unsigned short* w12b = (unsigned short*)W12r;        // 16384 bf16 [c][k] (32KB)
    unsigned short* h2b = (unsigned short*)out1;         // N*64 bf16 (first N*32 floats of out1)
    unsigned short* w2b = (unsigned short*)(out1 + (size_t)N * 64);  // 8192 bf16 (16KB, inside out1)

    // radix pass 1 + all weight prep in one launch (disjoint block ranges)
    k_bhist<<<NBLK + 66, 256, 0, stream>>>(dst, bh, E, nbkt, sums, NGRAPH * 64 + NGRAPH,
                                           lin1_w, lin1_b, conv1_w, conv2_w, w12b, c1pb, w2b);
    const int scanB = (M + SCAN_CHUNK - 1) / SCAN_CHUNK;          // 98 <= 256
    k_scan_part<<<scanB, 256, 0, stream>>>(bh, part, M);
    k_scan_mid<<<1, 256, 0, stream>>>(part, bh, scanB, M);        // also bh[M] = E
    k_scan_fin2<<<scanB, 256, 0, stream>>>(bh, part, bh, M);
    k_partition<<<NBLK, 256, 0, stream>>>(src, dst, bh, pairs, E, nbkt);
    k_csr_local<<<nbkt, 256, 0, stream>>>(pairs, bh, row_start, dis, col, N);

    // h1b = bf16(x @ W12 + c1pb) (MFMA, B direct from L2) + dropout bitmask
    const int gemmGrid = (N + 63) / 64;
    k_gemm_mfma<128><<<gemmGrid, 256, 0, stream>>>(x, w12b, c1pb, drop_u, dmask, h1b, N);

    // FUSED conv1 aggregation + dropout/relu + conv2 GEMM -> h2b
    // (two half-N dispatches: observability split, zero perf cost)
    const int nh = ((N / 2) + 15) & ~15;                 // 50000 (multiple of 16)
    k_gather_gemm2<<<nh / 16, 256, 0, stream>>>(h1b, row_start, col, dis, conv1_b,
                                                dmask, w2b, h2b, 0, nh);
    k_gather_gemm2<<<(N - nh + 15) / 16, 256, 0, stream>>>(h1b, row_start, col, dis, conv1_b,
                                                           dmask, w2b, h2b, nh, N);

    // conv2 aggregation fused with block-partial pooling (no hot atomics)
    k_gather_pool<<<nbGP, 256, 0, stream>>>(h2b, row_start, col, dis, conv2_b, batch,
                                            partial, bgid, bvcnt, sums, cntp, N);
    k_pool2<<<16, 256, 0, stream>>>(partial, bgid, bvcnt, sums, cntp, nbGP);

    // classifier
    k_final<<<NGRAPH, 64, 0, stream>>>(sums, cntp, lin2_w, lin2_b, out);
}

// Round 13
// 364.507 us; speedup vs baseline: 1.0681x; 1.0572x over previous
//
#include <hip/hip_runtime.h>
#include <hip/hip_bf16.h>

// Problem constants (fixed by the reference file)
#define DIN   128
#define HID2  64
#define NCLS  10
#define NGRAPH 128
#define SCAN_CHUNK 1024
#define NBLK 256          // blocks in bhist/partition (edge assignment must match)
#define NBKT_MAX 512      // max buckets (nodes/256)
#define CAP 6144          // LDS src-staging capacity per bucket (mean 4096, +32 sigma)
#define EPB 6400          // max edges per partition block = ceil(E/65536)*256 (E=1.6M)

typedef __attribute__((ext_vector_type(8))) short bf16x8;
typedef __attribute__((ext_vector_type(4))) float f32x4;

__device__ __forceinline__ void atomAddF(float* p, float v) {
    unsafeAtomicAdd(p, v);
}

// float -> bf16 (round-to-nearest-even), finite inputs.
__device__ __forceinline__ unsigned short f2bf(float f) {
    unsigned int u = __float_as_uint(f);
    u += 0x7fffu + ((u >> 16) & 1u);
    return (unsigned short)(u >> 16);
}

// ---------- combined prep + radix pass 1 ----------
// Blocks [0, NBLK): per-(bucket,block) histogram bh[bkt*NBLK + blk];
//   block 0 also zeroes the pooling accumulators.
// Blocks [NBLK, NBLK+65): w12b = bf16((lin1_w @ conv1_w)^T) (2 rows/block)
//   and c1preb = lin1_b @ conv1_w. w12b is stored [c][k] so the GEMM reads
//   B-fragments directly from L2 (no LDS tile, no bank conflicts).
// Block NBLK+65: w2b = bf16(conv2_w^T) for the fused gather+GEMM.
__global__ __launch_bounds__(256) void k_bhist(const int* __restrict__ dst,
                                               int* __restrict__ bh, int E, int nbkt,
                                               float* __restrict__ zbuf, int zn,
                                               const float* __restrict__ lw,
                                               const float* __restrict__ lb,
                                               const float* __restrict__ cw,
                                               const float* __restrict__ cw2,
                                               unsigned short* __restrict__ w12b,
                                               float* __restrict__ c1preb,
                                               unsigned short* __restrict__ w2b) {
    const int tid = threadIdx.x;
    if (blockIdx.x >= NBLK) {
        const int bi = blockIdx.x - NBLK;
        if (bi == 65) {
            // w2b[c*128+k] = bf16(cw2[k*64+c]); 32KB source, L2-hot
            for (int f = tid; f < 8192; f += 256) w2b[f] = f2bf(cw2[(f & 127) * 64 + (f >> 7)]);
        } else {
            const int i = bi * 2 + (tid >> 7);   // 0..129 (129 skipped)
            if (i <= 128) {
                const int j = tid & 127;
                const float* arow = (i < 128) ? (lw + i * 128) : lb;
                float acc = 0.f;
#pragma unroll 8
                for (int k = 0; k < 128; ++k) acc += arow[k] * cw[k * 128 + j];
                if (i < 128) w12b[j * 128 + i] = f2bf(acc);   // transposed bf16
                else         c1preb[j] = acc;
            }
        }
        return;
    }
    __shared__ int lh[NBKT_MAX];
    if (blockIdx.x == 0)
        for (int i = tid; i < zn; i += 256) zbuf[i] = 0.f;
    for (int i = tid; i < nbkt; i += 256) lh[i] = 0;
    __syncthreads();
    for (int e = blockIdx.x * 256 + tid; e < E; e += NBLK * 256)
        atomicAdd(&lh[__builtin_nontemporal_load(dst + e) >> 8], 1);
    __syncthreads();
    for (int i = tid; i < nbkt; i += 256) bh[i * NBLK + blockIdx.x] = lh[i];
}

// --- 3-phase parallel exclusive scan (generic length; used on bh in-place) ---
__global__ __launch_bounds__(256) void k_scan_part(const int* __restrict__ cnt,
                                                   int* __restrict__ part, int n) {
    int base = blockIdx.x * SCAN_CHUNK + threadIdx.x * 4;
    int s = 0;
#pragma unroll
    for (int j = 0; j < 4; ++j) { int i = base + j; if (i < n) s += cnt[i]; }
#pragma unroll
    for (int o = 32; o > 0; o >>= 1) s += __shfl_down(s, o);
    __shared__ int wsum[4];
    if ((threadIdx.x & 63) == 0) wsum[threadIdx.x >> 6] = s;
    __syncthreads();
    if (threadIdx.x == 0) part[blockIdx.x] = wsum[0] + wsum[1] + wsum[2] + wsum[3];
}
__global__ __launch_bounds__(256) void k_scan_mid(int* __restrict__ part,
                                                  int* __restrict__ total_out,
                                                  int B, int n) {
    __shared__ int sh[256];
    int t = threadIdx.x;
    int v = (t < B) ? part[t] : 0;
    sh[t] = v;
    __syncthreads();
    for (int off = 1; off < 256; off <<= 1) {
        int u = (t >= off) ? sh[t - off] : 0;
        __syncthreads();
        sh[t] += u;
        __syncthreads();
    }
    if (t < B) part[t] = sh[t] - v;
    if (t == 255) total_out[n] = sh[255];
}
// in-place-safe (out may alias cnt: all reads precede a barrier before writes)
__global__ __launch_bounds__(256) void k_scan_fin2(const int* cnt,
                                                   const int* __restrict__ part,
                                                   int* out, int n) {
    __shared__ int sh[256];
    int t = threadIdx.x;
    int base = blockIdx.x * SCAN_CHUNK + t * 4;
    int c[4]; int s = 0;
#pragma unroll
    for (int j = 0; j < 4; ++j) { int i = base + j; c[j] = (i < n) ? cnt[i] : 0; s += c[j]; }
    sh[t] = s;
    __syncthreads();
    for (int off = 1; off < 256; off <<= 1) {
        int u = (t >= off) ? sh[t - off] : 0;
        __syncthreads();
        sh[t] += u;
        __syncthreads();
    }
    int excl = part[blockIdx.x] + sh[t] - s;
#pragma unroll
    for (int j = 0; j < 4; ++j) {
        int i = base + j;
        if (i < n) out[i] = excl;
        excl += c[j];
    }
}

// Pass 2: in-LDS counting sort, then COALESCED write-out of packed
// (src<<8 | dst&255) edges. Edge->block assignment identical to k_bhist.
__global__ __launch_bounds__(256) void k_partition(const int* __restrict__ src,
                                                   const int* __restrict__ dst,
                                                   const int* __restrict__ bh,
                                                   int* __restrict__ pairs, int E, int nbkt) {
    __shared__ int lh[NBKT_MAX];
    __shared__ int lscan[NBKT_MAX + 2];
    __shared__ int gofs[NBKT_MAX];
    __shared__ int lcur[NBKT_MAX];
    __shared__ int scanw[256];
    __shared__ int lbuf[EPB];
    const int tid = threadIdx.x;
    const int b = blockIdx.x;

    for (int i = tid; i < NBKT_MAX; i += 256) lh[i] = 0;
    __syncthreads();
    for (int e = b * 256 + tid; e < E; e += NBLK * 256)
        atomicAdd(&lh[__builtin_nontemporal_load(dst + e) >> 8], 1);
    __syncthreads();
    const int a0 = lh[2 * tid], a1 = lh[2 * tid + 1];
    const int ps = a0 + a1;
    scanw[tid] = ps;
    __syncthreads();
    for (int off = 1; off < 256; off <<= 1) {
        int u = (tid >= off) ? scanw[tid - off] : 0;
        __syncthreads();
        scanw[tid] += u;
        __syncthreads();
    }
    const int ex = scanw[tid] - ps;
    lscan[2 * tid] = ex;
    lscan[2 * tid + 1] = ex + a0;
    if (tid == 255) lscan[512] = scanw[255];
    __syncthreads();
#pragma unroll
    for (int q = 0; q < 2; ++q) {
        const int k = 2 * tid + q;
        lcur[k] = lscan[k];
        if (k < nbkt) gofs[k] = bh[k * NBLK + b] - lscan[k];
    }
    __syncthreads();
    for (int e = b * 256 + tid; e < E; e += NBLK * 256) {
        const int d = __builtin_nontemporal_load(dst + e);
        const int s = __builtin_nontemporal_load(src + e);
        const int lpos = atomicAdd(&lcur[d >> 8], 1);
        lbuf[lpos] = (s << 8) | (d & 255);
    }
    __syncthreads();
    const int cnt = lscan[512];
    for (int i = tid; i < cnt; i += 256) {
        int lo = 0, hi = nbkt;
        while (hi - lo > 1) {
            const int mid = (lo + hi) >> 1;
            if (lscan[mid] <= i) lo = mid; else hi = mid;
        }
        pairs[gofs[lo] + i] = lbuf[i];
    }
}

// Pass 3: one block per bucket. In-LDS degree count + scan + scatter, then
// coalesced single-touch streams: row_start, dis, col. No global atomics.
__global__ __launch_bounds__(256) void k_csr_local(const int* __restrict__ pairs,
                                                   const int* __restrict__ bh,
                                                   int* __restrict__ row_start,
                                                   float* __restrict__ dis,
                                                   int* __restrict__ col,
                                                   int N) {
    __shared__ int cntL[256], scanL[256], curL[256];
    __shared__ int srcbuf[CAP];
    const int tid = threadIdx.x;
    const int lo = blockIdx.x << 8;
    const int bstart = bh[blockIdx.x * NBLK];
    const int bend = bh[(blockIdx.x + 1) * NBLK];   // last bucket: bh[nbkt*NBLK] == E
    const int nE = bend - bstart;

    cntL[tid] = 0;
    __syncthreads();
    for (int e = bstart + tid; e < bend; e += 256)
        atomicAdd(&cntL[pairs[e] & 255], 1);
    __syncthreads();
    const int deg = cntL[tid];
    scanL[tid] = deg;
    __syncthreads();
    for (int off = 1; off < 256; off <<= 1) {
        int u = (tid >= off) ? scanL[tid - off] : 0;
        __syncthreads();
        scanL[tid] += u;
        __syncthreads();
    }
    const int excl = scanL[tid] - deg;
    curL[tid] = excl;
    const int node = lo + tid;
    if (node < N) {
        row_start[node] = bstart + excl;
        dis[node] = rsqrtf((float)(deg + 1));   // +1 self-loop
    } else if (node == N) {
        row_start[N] = bend;                    // == E (only last bucket reaches here)
    }
    __syncthreads();
    if (nE <= CAP) {
        for (int e = bstart + tid; e < bend; e += 256) {
            int p = pairs[e];
            int pos = atomicAdd(&curL[p & 255], 1);
            srcbuf[pos] = ((unsigned int)p) >> 8;
        }
        __syncthreads();
        for (int i = tid; i < nE; i += 256)
            col[bstart + i] = srcbuf[i];
    } else {  // overflow fallback (statistically never for random graphs)
        for (int e = bstart + tid; e < bend; e += 256) {
            int p = pairs[e];
            int pos = atomicAdd(&curL[p & 255], 1);
            col[bstart + pos] = ((unsigned int)p) >> 8;
        }
    }
}

// ---------- MFMA bf16 GEMM (fp32 A, bf16 pre-transposed W in L2): ----------
// out = bf16(A @ W + bias); also emits the dropout bitmask for its 32 rows.
// 32-ROW TILES (r12 PMC: 64-row tiles gave only 1563 blocks = 6.1/CU ->
// occupancy 31%, latency-bound at 1.4 TB/s. 32-row tiles double the block
// pool to 3125 (12.2/CU), halve LDS to 8.7KB, and shorten the per-block
// stage->sync->MFMA critical path — same bytes, same FLOPs, bit-identical.)
template <int NCOL>
__global__ __launch_bounds__(256) void k_gemm_mfma(const float* __restrict__ A,
                                                   const unsigned short* __restrict__ Wb,
                                                   const float* __restrict__ bias,
                                                   const float* __restrict__ du,
                                                   unsigned int* __restrict__ dmask,
                                                   unsigned short* __restrict__ out, int M) {
    constexpr int KP = 136;
    __shared__ unsigned short As[32 * KP];

    const int tid = threadIdx.x;
    const int row0 = blockIdx.x * 32;

    // stage 32 rows x 128 cols (4 float4 per thread, interleaved convert/store)
    for (int f = tid; f < 1024; f += 256) {
        const int r = f >> 5, c4 = f & 31;
        const int gr = row0 + r;
        float4 v = make_float4(0.f, 0.f, 0.f, 0.f);
        if (gr < M) v = *(const float4*)(A + (size_t)gr * 128 + c4 * 4);
        ushort4 b;
        b.x = f2bf(v.x); b.y = f2bf(v.y); b.z = f2bf(v.z); b.w = f2bf(v.w);
        *(ushort4*)(&As[r * KP + c4 * 4]) = b;
    }
    // fused dropout-bitmask: threads 0..127 -> row (t>>2), word (t&3)
    if (dmask && tid < 128) {
        const int gr = row0 + (tid >> 2), w = tid & 3;
        if (gr < M) {
            const float* p = du + (size_t)gr * 128 + w * 32;
            unsigned int m = 0;
#pragma unroll
            for (int jj = 0; jj < 8; ++jj) {
                const float4 v = *(const float4*)(p + jj * 4);
                m |= (v.x >= 0.5f ? 1u : 0u) << (jj * 4 + 0);
                m |= (v.y >= 0.5f ? 1u : 0u) << (jj * 4 + 1);
                m |= (v.z >= 0.5f ? 1u : 0u) << (jj * 4 + 2);
                m |= (v.w >= 0.5f ? 1u : 0u) << (jj * 4 + 3);
            }
            dmask[gr * 4 + w] = m;
        }
    }
    __syncthreads();

    const int wave = tid >> 6, lane = tid & 63;
    const int quad = lane >> 4, l16 = lane & 15;
    constexpr int CT = (NCOL == 128) ? 2 : 1;
    const int col0 = wave * 16 * CT;

    f32x4 acc[2][CT];
#pragma unroll
    for (int rt = 0; rt < 2; ++rt)
#pragma unroll
        for (int ct = 0; ct < CT; ++ct) acc[rt][ct] = 0.f;

#pragma unroll
    for (int ks = 0; ks < 4; ++ks) {
        const int kbase = ks * 32 + quad * 8;
        bf16x8 bfr[CT];
#pragma unroll
        for (int ct = 0; ct < CT; ++ct)
            bfr[ct] = *(const bf16x8*)(&Wb[(size_t)(col0 + ct * 16 + l16) * 128 + kbase]);
#pragma unroll
        for (int rt = 0; rt < 2; ++rt) {
            bf16x8 afr = *(const bf16x8*)(&As[(rt * 16 + l16) * KP + kbase]);
#pragma unroll
            for (int ct = 0; ct < CT; ++ct)
                acc[rt][ct] = __builtin_amdgcn_mfma_f32_16x16x32_bf16(afr, bfr[ct], acc[rt][ct], 0, 0, 0);
        }
    }

#pragma unroll
    for (int rt = 0; rt < 2; ++rt)
#pragma unroll
        for (int ct = 0; ct < CT; ++ct) {
            const int c = col0 + ct * 16 + l16;
            const float bv = bias ? bias[c] : 0.f;
#pragma unroll
            for (int reg = 0; reg < 4; ++reg) {
                const int gr = row0 + rt * 16 + quad * 4 + reg;
                if (gr < M) out[(size_t)gr * NCOL + c] = f2bf(acc[rt][ct][reg] + bv);
            }
        }
}

// ---------- CSR gather (bf16 input rows, fp32 accumulate) ----------
__device__ __forceinline__ void bfacc(uint4 v, float d, float* acc) {
    acc[0] = fmaf(d, __uint_as_float(v.x << 16),        acc[0]);
    acc[1] = fmaf(d, __uint_as_float(v.x & 0xffff0000u), acc[1]);
    acc[2] = fmaf(d, __uint_as_float(v.y << 16),        acc[2]);
    acc[3] = fmaf(d, __uint_as_float(v.y & 0xffff0000u), acc[3]);
    acc[4] = fmaf(d, __uint_as_float(v.z << 16),        acc[4]);
    acc[5] = fmaf(d, __uint_as_float(v.z & 0xffff0000u), acc[5]);
    acc[6] = fmaf(d, __uint_as_float(v.w << 16),        acc[6]);
    acc[7] = fmaf(d, __uint_as_float(v.w & 0xffff0000u), acc[7]);
}

// FUSED: conv1 aggregation + dropout/relu + conv2 GEMM (proven 66.5us form,
// single launch as in the best-measured round 10).
__global__ __launch_bounds__(256) void k_gather_gemm2(const unsigned short* __restrict__ h,
                                                      const int* __restrict__ row_start,
                                                      const int* __restrict__ col,
                                                      const float* __restrict__ dis,
                                                      const float* __restrict__ bias,
                                                      const unsigned int* __restrict__ dmask,
                                                      const unsigned short* __restrict__ w2b,
                                                      unsigned short* __restrict__ h2b,
                                                      int n) {
    constexpr int KP = 136;
    __shared__ unsigned short As[16 * KP];
    __shared__ unsigned short Wt[64 * KP];
    const int tid = threadIdx.x;
    const int node0 = blockIdx.x * 16;
    const int node = node0 + (tid >> 4);
    const int l = tid & 15;
    const int coff = l * 8;

    for (int f = tid * 4; f < 8192; f += 1024) {
        const int c = f >> 7, k = f & 127;
        *(ushort4*)(&Wt[c * KP + k]) = *(const ushort4*)(&w2b[f]);
    }

    float r[8];
    if (node < n) {
        const float dn = dis[node];
        const unsigned int mword = dmask[node * 4 + (l >> 2)];
        const unsigned int mbyte = (mword >> ((l & 3) * 8)) & 0xffu;
        float acc[8];
        {
            uint4 v = *(const uint4*)(h + (size_t)node * 128 + coff);
#pragma unroll
            for (int q = 0; q < 8; ++q) acc[q] = 0.f;
            bfacc(v, dn, acc);
        }
        const int beg = row_start[node], end = row_start[node + 1];
        int j = beg;
        for (; j + 3 < end; j += 4) {
            const int s0 = col[j], s1 = col[j + 1], s2 = col[j + 2], s3 = col[j + 3];
            const float d0 = dis[s0], d1 = dis[s1], d2 = dis[s2], d3 = dis[s3];
            const uint4 v0 = *(const uint4*)(h + (size_t)s0 * 128 + coff);
            const uint4 v1 = *(const uint4*)(h + (size_t)s1 * 128 + coff);
            const uint4 v2 = *(const uint4*)(h + (size_t)s2 * 128 + coff);
            const uint4 v3 = *(const uint4*)(h + (size_t)s3 * 128 + coff);
            bfacc(v0, d0, acc);
            bfacc(v1, d1, acc);
            bfacc(v2, d2, acc);
            bfacc(v3, d3, acc);
        }
        for (; j < end; ++j) {
            const int s0 = col[j];
            const float d0 = dis[s0];
            const uint4 v0 = *(const uint4*)(h + (size_t)s0 * 128 + coff);
            bfacc(v0, d0, acc);
        }
        const float4 b0 = *(const float4*)(bias + coff);
        const float4 b1 = *(const float4*)(bias + coff + 4);
        r[0] = fmaf(dn, acc[0], b0.x); r[1] = fmaf(dn, acc[1], b0.y);
        r[2] = fmaf(dn, acc[2], b0.z); r[3] = fmaf(dn, acc[3], b0.w);
        r[4] = fmaf(dn, acc[4], b1.x); r[5] = fmaf(dn, acc[5], b1.y);
        r[6] = fmaf(dn, acc[6], b1.z); r[7] = fmaf(dn, acc[7], b1.w);
        // dropout p=0.5 (keep-bit from dmask, x2) then relu; power-of-2 scale
        // commutes with RNE-to-bf16 -> bit-identical to the unfused path.
#pragma unroll
        for (int q = 0; q < 8; ++q)
            r[q] = ((mbyte >> q) & 1u) ? 2.f * fmaxf(r[q], 0.f) : 0.f;
    } else {
#pragma unroll
        for (int q = 0; q < 8; ++q) r[q] = 0.f;
    }
    ushort4 o0, o1;
    o0.x = f2bf(r[0]); o0.y = f2bf(r[1]); o0.z = f2bf(r[2]); o0.w = f2bf(r[3]);
    o1.x = f2bf(r[4]); o1.y = f2bf(r[5]); o1.z = f2bf(r[6]); o1.w = f2bf(r[7]);
    *(ushort4*)(&As[(tid >> 4) * KP + coff]) = o0;
    *(ushort4*)(&As[(tid >> 4) * KP + coff + 4]) = o1;
    __syncthreads();

    const int wave = tid >> 6, lane = tid & 63;
    const int quad = lane >> 4, l16 = lane & 15;
    const int c0 = wave * 16;
    f32x4 a2 = 0.f;
#pragma unroll
    for (int ks = 0; ks < 4; ++ks) {
        const int kbase = ks * 32 + quad * 8;
        bf16x8 afr = *(const bf16x8*)(&As[l16 * KP + kbase]);
        bf16x8 bfr = *(const bf16x8*)(&Wt[(c0 + l16) * KP + kbase]);
        a2 = __builtin_amdgcn_mfma_f32_16x16x32_bf16(afr, bfr, a2, 0, 0, 0);
    }
#pragma unroll
    for (int reg = 0; reg < 4; ++reg) {
        const int gr = node0 + quad * 4 + reg;
        if (gr < n) h2b[(size_t)gr * 64 + c0 + l16] = f2bf(a2[reg]);
    }
}

// conv2 gather fused with pooling. 8 lanes/node, 32 nodes/block; uniform
// blocks emit one partial row, no hot atomics.
__global__ __launch_bounds__(256) void k_gather_pool(const unsigned short* __restrict__ h,
                                                     const int* __restrict__ row_start,
                                                     const int* __restrict__ col,
                                                     const float* __restrict__ dis,
                                                     const float* __restrict__ bias,
                                                     const int* __restrict__ batch,
                                                     float* __restrict__ partial,
                                                     int* __restrict__ bgid,
                                                     int* __restrict__ bvcnt,
                                                     float* __restrict__ sums,
                                                     float* __restrict__ cnt, int n) {
    __shared__ float bsum[4][64];
    __shared__ int sh_gfirst, sh_uni;
    const int tid = threadIdx.x;
    const int node = (blockIdx.x * 256 + tid) >> 3;
    const int l = tid & 7;
    const int coff = l * 8;
    const bool valid = node < n;
    const int node0 = blockIdx.x * 32;

    if (tid == 0) { sh_gfirst = batch[node0]; sh_uni = 1; }
    __syncthreads();
    const int gfirst = sh_gfirst;

    float r[8];
    int g = gfirst;
    if (valid) {
        const float dn = dis[node];
        g = batch[node];
        float acc[8];
        {
            uint4 v = *(const uint4*)(h + (size_t)node * 64 + coff);
#pragma unroll
            for (int q = 0; q < 8; ++q) acc[q] = 0.f;
            bfacc(v, dn, acc);
        }
        const int beg = row_start[node], end = row_start[node + 1];
        int j = beg;
        for (; j + 3 < end; j += 4) {
            const int s0 = col[j], s1 = col[j + 1], s2 = col[j + 2], s3 = col[j + 3];
            const float d0 = dis[s0], d1 = dis[s1], d2 = dis[s2], d3 = dis[s3];
            const uint4 v0 = *(const uint4*)(h + (size_t)s0 * 64 + coff);
            const uint4 v1 = *(const uint4*)(h + (size_t)s1 * 64 + coff);
            const uint4 v2 = *(const uint4*)(h + (size_t)s2 * 64 + coff);
            const uint4 v3 = *(const uint4*)(h + (size_t)s3 * 64 + coff);
            bfacc(v0, d0, acc);
            bfacc(v1, d1, acc);
            bfacc(v2, d2, acc);
            bfacc(v3, d3, acc);
        }
        for (; j < end; ++j) {
            const int s0 = col[j];
            const float d0 = dis[s0];
            const uint4 v0 = *(const uint4*)(h + (size_t)s0 * 64 + coff);
            bfacc(v0, d0, acc);
        }
        const float4 b0 = *(const float4*)(bias + coff);
        const float4 b1 = *(const float4*)(bias + coff + 4);
        r[0] = fmaf(dn, acc[0], b0.x); r[1] = fmaf(dn, acc[1], b0.y);
        r[2] = fmaf(dn, acc[2], b0.z); r[3] = fmaf(dn, acc[3], b0.w);
        r[4] = fmaf(dn, acc[4], b1.x); r[5] = fmaf(dn, acc[5], b1.y);
        r[6] = fmaf(dn, acc[6], b1.z); r[7] = fmaf(dn, acc[7], b1.w);
    } else {
#pragma unroll
        for (int q = 0; q < 8; ++q) r[q] = 0.f;
    }

    if (valid && g != gfirst) atomicAnd(&sh_uni, 0);
    __syncthreads();

    if (sh_uni) {
        // whole block one graph: wave xor-reduce -> LDS -> one partial row
#pragma unroll
        for (int q = 0; q < 8; ++q) {
            r[q] += __shfl_xor(r[q], 8);
            r[q] += __shfl_xor(r[q], 16);
            r[q] += __shfl_xor(r[q], 32);
        }
        const int wave = tid >> 6, lane = tid & 63;
        if (lane < 8) {
#pragma unroll
            for (int q = 0; q < 8; ++q) bsum[wave][lane * 8 + q] = r[q];
        }
        __syncthreads();
        if (tid < 64)
            partial[(size_t)blockIdx.x * 64 + tid] =
                bsum[0][tid] + bsum[1][tid] + bsum[2][tid] + bsum[3][tid];
        if (tid == 0) {
            bgid[blockIdx.x] = gfirst;
            bvcnt[blockIdx.x] = min(n - node0, 32);
        }
    } else {
        if (tid == 0) bgid[blockIdx.x] = -1;
        const int g0 = __shfl(g, 0);
        const bool wuni = __all(valid && (g == g0));
        if (wuni) {
#pragma unroll
            for (int q = 0; q < 8; ++q) {
                r[q] += __shfl_xor(r[q], 8);
                r[q] += __shfl_xor(r[q], 16);
                r[q] += __shfl_xor(r[q], 32);
            }
            const int lane = tid & 63;
            if (lane < 8) {
#pragma unroll
                for (int q = 0; q < 8; ++q) atomAddF(&sums[g0 * 64 + lane * 8 + q], r[q]);
                if (lane == 0) atomAddF(&cnt[g0], 8.0f);
            }
        } else if (valid) {
#pragma unroll
            for (int q = 0; q < 8; ++q) atomAddF(&sums[g * 64 + coff + q], r[q]);
            if (l == 0) atomAddF(&cnt[g], 1.0f);
        }
    }
}

// Stage 2: run-accumulate the (sorted-by-construction) per-block partial rows.
__global__ __launch_bounds__(256) void k_pool2(const float* __restrict__ partial,
                                               const int* __restrict__ bgid,
                                               const int* __restrict__ bvcnt,
                                               float* __restrict__ sums,
                                               float* __restrict__ cnt, int nb) {
    const int grp = (blockIdx.x * 256 + (int)threadIdx.x) >> 6;
    const int f = threadIdx.x & 63;
    const int ngroups = gridDim.x * 4;
    const int per = (nb + ngroups - 1) / ngroups;
    const int start = grp * per, end = min(nb, start + per);
    if (start >= end) return;
    int cg = -1;
    float acc = 0.f;
    int vc = 0;
    for (int b = start; b < end; ++b) {
        const int g = bgid[b];
        if (g != cg) {
            if (cg >= 0) {
                atomAddF(&sums[cg * 64 + f], acc);
                if (f == 0) atomAddF(&cnt[cg], (float)vc);
            }
            acc = 0.f; vc = 0; cg = g;
        }
        if (g >= 0) {
            acc += partial[(size_t)b * 64 + f];
            vc += bvcnt[b];
        }
    }
    if (cg >= 0) {
        atomAddF(&sums[cg * 64 + f], acc);
        if (f == 0) atomAddF(&cnt[cg], (float)vc);
    }
}

// ---------- final ----------
__global__ __launch_bounds__(64) void k_final(const float* __restrict__ sums,
                                              const float* __restrict__ cnt,
                                              const float* __restrict__ w,
                                              const float* __restrict__ b,
                                              float* __restrict__ out) {
    int g = blockIdx.x, f = threadIdx.x;
    float c = fmaxf(cnt[g], 1.0f);
    float p = sums[g * 64 + f] / c;
#pragma unroll
    for (int cls = 0; cls < NCLS; ++cls) {
        float v = p * w[f * 10 + cls];
#pragma unroll
        for (int o = 32; o > 0; o >>= 1) v += __shfl_down(v, o);
        if (f == 0) out[g * 10 + cls] = v + b[cls];
    }
}

extern "C" void kernel_launch(void* const* d_in, const int* in_sizes, int n_in,
                              void* d_out, int out_size, void* d_ws, size_t ws_size,
                              hipStream_t stream) {
    const float* x       = (const float*)d_in[0];
    const int*   ei      = (const int*)d_in[1];
    const int*   batch   = (const int*)d_in[2];
    const float* drop_u  = (const float*)d_in[4];
    const float* lin1_w  = (const float*)d_in[5];
    const float* lin1_b  = (const float*)d_in[6];
    const float* conv1_w = (const float*)d_in[7];
    const float* conv1_b = (const float*)d_in[8];
    const float* conv2_w = (const float*)d_in[9];
    const float* conv2_b = (const float*)d_in[10];
    const float* lin2_w  = (const float*)d_in[11];
    const float* lin2_b  = (const float*)d_in[12];
    float* out = (float*)d_out;

    const int N = in_sizes[0] / DIN;        // 100000
    const int E = in_sizes[1] / 2;          // 1600000
    const int* src = ei;
    const int* dst = ei + E;

    const int nbkt = (N + 255) >> 8;        // 391
    const int M = nbkt * NBLK;              // bh scan length
    const int nbGP = (int)(((size_t)N * 8 + 255) / 256);   // gather_pool blocks (3125)

    // workspace layout (float units) — identical footprint to passing round 12.
    float* ws    = (float*)d_ws;
    float* out1  = ws;                                   // N*128 region (h2b + w2b live here)
    unsigned short* h1b = (unsigned short*)(ws + (size_t)N * 128);   // N*128 bf16
    float* dis   = ws + (size_t)N * 128 + (size_t)N * 64;            // N
    float* W12r  = dis + N;                              // 16384 floats (w12b lives here: 32KB)
    float* c1pb  = W12r + 16384;                         // 128
    float* sums  = c1pb + 128;                           // 8192
    float* cntp  = sums + NGRAPH * 64;                   // 128
    int*   row_start = (int*)(cntp + NGRAPH);            // N+2 (padded)
    int*   part  = row_start + N + 2;                    // 256
    int*   bh    = part + 256;                           // NBKT_MAX*NBLK+2
    int*   col   = bh + NBKT_MAX * NBLK + 2;             // E
    int*   pairs = col + E;                              // E (packed src<<8|dst&255)
    float* partial = (float*)(pairs + E);                // nbGP*64
    int*   bgid  = (int*)(partial + (size_t)nbGP * 64);  // nbGP
    int*   bvcnt = bgid + nbGP;                          // nbGP
    unsigned int* dmask = (unsigned int*)pairs;          // N*4 words — ALIASES pairs (dead after csr_local)
    unsigned short* w12b = (unsigned short*)W12r;        // 16384 bf16 [c][k] (32KB)
    unsigned short* h2b = (unsigned short*)out1;         // N*64 bf16 (first N*32 floats of out1)
    unsigned short* w2b = (unsigned short*)(out1 + (size_t)N * 64);  // 8192 bf16 (16KB, inside out1)

    // radix pass 1 + all weight prep in one launch (disjoint block ranges)
    k_bhist<<<NBLK + 66, 256, 0, stream>>>(dst, bh, E, nbkt, sums, NGRAPH * 64 + NGRAPH,
                                           lin1_w, lin1_b, conv1_w, conv2_w, w12b, c1pb, w2b);
    const int scanB = (M + SCAN_CHUNK - 1) / SCAN_CHUNK;          // 98 <= 256
    k_scan_part<<<scanB, 256, 0, stream>>>(bh, part, M);
    k_scan_mid<<<1, 256, 0, stream>>>(part, bh, scanB, M);        // also bh[M] = E
    k_scan_fin2<<<scanB, 256, 0, stream>>>(bh, part, bh, M);
    k_partition<<<NBLK, 256, 0, stream>>>(src, dst, bh, pairs, E, nbkt);
    k_csr_local<<<nbkt, 256, 0, stream>>>(pairs, bh, row_start, dis, col, N);

    // h1b = bf16(x @ W12 + c1pb) (MFMA, 32-row tiles, B direct from L2) + dmask
    const int gemmGrid = (N + 31) / 32;                  // 3125 blocks
    k_gemm_mfma<128><<<gemmGrid, 256, 0, stream>>>(x, w12b, c1pb, drop_u, dmask, h1b, N);

    // FUSED conv1 aggregation + dropout/relu + conv2 GEMM -> h2b (single launch)
    k_gather_gemm2<<<(N + 15) / 16, 256, 0, stream>>>(h1b, row_start, col, dis, conv1_b,
                                                      dmask, w2b, h2b, N);

    // conv2 aggregation fused with block-partial pooling (no hot atomics)
    k_gather_pool<<<nbGP, 256, 0, stream>>>(h2b, row_start, col, dis, conv2_b, batch,
                                            partial, bgid, bvcnt, sums, cntp, N);
    k_pool2<<<16, 256, 0, stream>>>(partial, bgid, bvcnt, sums, cntp, nbGP);

    // classifier
    k_final<<<NGRAPH, 64, 0, stream>>>(sums, cntp, lin2_w, lin2_b, out);
}